// Round 16
// baseline (508.679 us; speedup 1.0000x reference)
//
#include <hip/hip_runtime.h>
#include <stdint.h>

#define NB3 8112
#define NB4 2028
#define NB5 507
#define NTOT 10647           // 8112 + 2028 + 507
#define NBATCH 4
#define NCLS 20
#define NW32 333             // ceil(10647 / 32)
#define NW64 167             // ceil(10647 / 64)
#define NPAIR 84             // ceil(NW64 / 2): 128-box groups for resolve
#define NTAIL 23             // NTOT - 64*(NW64-1)
#define RCH 11               // rank: element chunks of 1024 (256 thr x 4 keys)
#define RSL 6                // rank: tile slices
#define RTP 7                // rank: 256-key tiles per slice (6*7*256 >= NTOT)
#define LDS_CAP 9984         // boxes staged in LDS (fallback kernel)
#define CONF_THR_F 0.1f
#define IOU_THR_F 0.45f
// Upper midpoint of 0.45f: RN(x) > 0.45f  <=>  x > IOU_MID (0.45f mantissa LSB
// is even -> tie at the midpoint rounds DOWN). 25-bit m x 24-bit union is
// exact in f64, so (double)inter > IOU_MID*(double)union is bit-equivalent to
// the reference's f32-divide-then-compare.
#define IOU_MID ((double)IOU_THR_F + 0x1p-26)

typedef unsigned long long u64;

// ---------------------------------------------------------------------------
// Kernel A: per-box score / class argmax / sort key.
// Also zeroes nvalid/rank (folds memsets).
// ---------------------------------------------------------------------------
__global__ void prep_kernel(const float* __restrict__ p3b, const float* __restrict__ p3c, const float* __restrict__ p3k,
                            const float* __restrict__ p4b, const float* __restrict__ p4c, const float* __restrict__ p4k,
                            const float* __restrict__ p5b, const float* __restrict__ p5c, const float* __restrict__ p5k,
                            uint64_t* __restrict__ keys, float4* __restrict__ boxes_cat,
                            float* __restrict__ score, int* __restrict__ clsidx, uint32_t* __restrict__ svout,
                            int* __restrict__ nvalid, int* __restrict__ rank)
{
#pragma clang fp contract(off)
    int idx = blockIdx.x * 256 + threadIdx.x;
    if (idx < NBATCH) nvalid[idx] = 0;
    if (idx >= NBATCH * NTOT) return;
    rank[idx] = 0;
    int b = idx / NTOT;
    int i = idx - b * NTOT;

    const float* bx; const float* cf; const float* cl; int n, off;
    if (i < NB3)            { bx = p3b; cf = p3c; cl = p3k; n = NB3; off = i; }
    else if (i < NB3 + NB4) { bx = p4b; cf = p4c; cl = p4k; n = NB4; off = i - NB3; }
    else                    { bx = p5b; cf = p5c; cl = p5k; n = NB5; off = i - NB3 - NB4; }

    size_t e = (size_t)b * n + off;
    float4 box = *(const float4*)(bx + e * 4);
    float conf = cf[e];
    const float* c = cl + e * NCLS;
    float m = c[0]; int mi = 0;
    #pragma unroll
    for (int k = 1; k < NCLS; ++k) { float v = c[k]; if (v > m) { m = v; mi = k; } }

    bool valid = conf > CONF_THR_F;
    float s = valid ? conf * m : 0.0f;           // exact: single f32 mul, no fma
    uint32_t sb = __float_as_uint(s);            // s >= 0 -> bits monotonic
    keys[idx]      = ((uint64_t)sb << 32) | (uint32_t)(0xFFFFFFFFu - (uint32_t)i);
    boxes_cat[idx] = box;
    score[idx]     = s;
    clsidx[idx]    = mi;
    svout[idx]     = valid ? 1u : 0u;
}

// ---------------------------------------------------------------------------
// Kernel B1: 2D-decomposed partial rank (proven R13/R14), with the LDS tile
// read vectorized (ulonglong2: 8 compares per LDS access instead of 4).
// ---------------------------------------------------------------------------
__global__ void __launch_bounds__(256) rank_partial(const uint64_t* __restrict__ keys,
                                                    int* __restrict__ rank)
{
    int b = blockIdx.z;
    const uint64_t* kb = keys + (size_t)b * NTOT;
    int i0 = blockIdx.x * 1024 + threadIdx.x;
    uint64_t k0 = (i0       < NTOT) ? kb[i0]       : 0ull;
    uint64_t k1 = (i0 + 256 < NTOT) ? kb[i0 + 256] : 0ull;
    uint64_t k2 = (i0 + 512 < NTOT) ? kb[i0 + 512] : 0ull;
    uint64_t k3 = (i0 + 768 < NTOT) ? kb[i0 + 768] : 0ull;
    int r0 = 0, r1 = 0, r2 = 0, r3 = 0;

    __shared__ ulonglong2 tile2[128];
    uint64_t* tile = (uint64_t*)tile2;
    for (int tt = 0; tt < RTP; ++tt) {
        int j = (blockIdx.y * RTP + tt) * 256 + threadIdx.x;
        tile[threadIdx.x] = (j < NTOT) ? kb[j] : 0ull;   // 0 never > any real key
        __syncthreads();
        #pragma unroll 4
        for (int t = 0; t < 128; ++t) {
            ulonglong2 kt = tile2[t];
            r0 += ((kt.x > k0) ? 1 : 0) + ((kt.y > k0) ? 1 : 0);
            r1 += ((kt.x > k1) ? 1 : 0) + ((kt.y > k1) ? 1 : 0);
            r2 += ((kt.x > k2) ? 1 : 0) + ((kt.y > k2) ? 1 : 0);
            r3 += ((kt.x > k3) ? 1 : 0) + ((kt.y > k3) ? 1 : 0);
        }
        __syncthreads();
    }

    int* rb = rank + (size_t)b * NTOT;
    if (i0       < NTOT) atomicAdd(&rb[i0],       r0);
    if (i0 + 256 < NTOT) atomicAdd(&rb[i0 + 256], r1);
    if (i0 + 512 < NTOT) atomicAdd(&rb[i0 + 512], r2);
    if (i0 + 768 < NTOT) atomicAdd(&rb[i0 + 768], r3);
}

// ---------------------------------------------------------------------------
// Kernel B2: invert the permutation (proven R14). 4B scattered store only.
// ---------------------------------------------------------------------------
__global__ void inv_kernel(const int* __restrict__ rank, int* __restrict__ inv)
{
    int idx = blockIdx.x * 256 + threadIdx.x;
    if (idx >= NBATCH * NTOT) return;
    int b = idx / NTOT;
    int i = idx - b * NTOT;
    inv[(size_t)b * NTOT + rank[idx]] = i;
}

// ---------------------------------------------------------------------------
// Kernel B3: gather into sorted arrays (proven R14). Random L2-resident reads
// + coalesced writes. nvalid only when fallback path needs it.
// ---------------------------------------------------------------------------
__global__ void gather_kernel(const int* __restrict__ inv,
                              const float4* __restrict__ boxes_cat,
                              const float* __restrict__ score,
                              const int* __restrict__ clsidx,
                              const uint32_t* __restrict__ sv,
                              float4* __restrict__ sboxes, float* __restrict__ sscore,
                              int* __restrict__ scls, uint32_t* __restrict__ ssv,
                              int* __restrict__ nvalid, int need_nvalid)
{
    int idx = blockIdx.x * 256 + threadIdx.x;
    if (idx >= NBATCH * NTOT) return;
    int b = idx / NTOT;
    int i = idx - b * NTOT;
    size_t base = (size_t)b * NTOT;
    int src = inv[idx];
    float4 box = boxes_cat[base + src];
    uint32_t v = sv[base + src];
    sboxes[idx] = box;
    sscore[idx] = score[base + src];
    scls[idx]   = clsidx[base + src];
    ssv[idx]    = v;
    if (need_nvalid) {
        int mv = v ? (i + 1) : 0;
        #pragma unroll
        for (int d = 32; d >= 1; d >>= 1) {
            int o = __shfl_xor(mv, d, 64);
            mv = (o > mv) ? o : mv;
        }
        if ((threadIdx.x & 63) == 0 && mv > 0) atomicMax(&nvalid[b], mv);
    }
}

// ---------------------------------------------------------------------------
// Kernel C1 (fast path): build suppression bit-matrix + band buffers.
// IoU predicate via exact f64 midpoint comparison (see IOU_MID).
// mask[(b*NTOT + i)*NW64 + c]: bit k set iff hit && c*64+k > i && c*64+k < NTOT.
// ldiag [(b*NW64+r)*64+lane] = raw hit row & ((1<<lane)-1).
// s1..s5diag[(b*NW64+r)*64+lane] = mask word at column r+1..r+5.
// lt1[(b*NPAIR+p)*64+lane] = transpose of the (r=2p, c=2p+1) block (bit-
// symmetric hit predicate) for the joint 128-box fixpoint.
// ---------------------------------------------------------------------------
__global__ void __launch_bounds__(256) mask_build(const float4* __restrict__ sboxes,
                                                  u64* __restrict__ mask,
                                                  u64* __restrict__ ldiag,
                                                  u64* __restrict__ s1diag,
                                                  u64* __restrict__ s2diag,
                                                  u64* __restrict__ s3diag,
                                                  u64* __restrict__ s4diag,
                                                  u64* __restrict__ s5diag,
                                                  u64* __restrict__ lt1)
{
#pragma clang fp contract(off)
    int c = blockIdx.y;
    if (c < blockIdx.x * 4) return;              // whole block below diagonal
    int b = blockIdx.z;
    int sub = threadIdx.x >> 6;
    int lane = threadIdx.x & 63;
    int r = blockIdx.x * 4 + sub;

    __shared__ float4 cb[64];
    __shared__ float  ca[64];
    if (threadIdx.x < 64) {
        int j = c * 64 + threadIdx.x;
        float4 bj = sboxes[(size_t)b * NTOT + (j < NTOT ? j : NTOT - 1)];
        cb[threadIdx.x] = bj;
        ca[threadIdx.x] = (bj.z - bj.x) * (bj.w - bj.y);
    }
    __syncthreads();

    if (r >= NW64 || c < r) return;              // wave below diagonal / OOB
    int i = r * 64 + lane;
    float4 bi = sboxes[(size_t)b * NTOT + (i < NTOT ? i : NTOT - 1)];
    float ax1 = bi.x, ay1 = bi.y, ax2 = bi.z, ay2 = bi.w;
    float area_i = (ax2 - ax1) * (ay2 - ay1);

    u64 hh = 0;
    #pragma unroll 8
    for (int k = 0; k < 64; ++k) {
        float4 bj = cb[k];
        float xx1 = fmaxf(bj.x, ax1);
        float yy1 = fmaxf(bj.y, ay1);
        float xx2 = fminf(bj.z, ax2);
        float yy2 = fminf(bj.w, ay2);
        float w = fmaxf(xx2 - xx1, 0.0f);
        float h = fmaxf(yy2 - yy1, 0.0f);
        float inter = w * h;
        float uni = (area_i + ca[k]) - inter;    // same f32 ops as reference
        bool hit = (double)inter > IOU_MID * (double)uni;   // == RN(inter/uni) > 0.45f
        hh |= (u64)hit << k;
    }

    u64 colmask = (c == NW64 - 1) ? ((1ull << NTAIL) - 1) : ~0ull;
    u64 mw = hh & colmask;

    if (i < NTOT) {
        size_t bl = ((size_t)b * NW64 + r) * 64 + lane;
        if (c == r) {
            u64 gtmask = (lane < 63) ? (~0ull << (lane + 1)) : 0ull;
            mask[((size_t)b * NTOT + i) * NW64 + c] = mw & gtmask;
            ldiag[bl] = hh & ((1ull << lane) - 1);
        } else {
            mask[((size_t)b * NTOT + i) * NW64 + c] = mw;
            if (c == r + 1) s1diag[bl] = mw;
            if (c == r + 2) s2diag[bl] = mw;
            if (c == r + 3) s3diag[bl] = mw;
            if (c == r + 4) s4diag[bl] = mw;
            if (c == r + 5) s5diag[bl] = mw;
        }
    }
    // transposed band for the joint pair fixpoint (even r, c = r+1 only).
    if (c == r + 1 && (r & 1) == 0) {
        u64 ltw = 0;
        #pragma unroll 8
        for (int k = 0; k < 64; ++k) {
            u64 bw = __ballot((mw >> k) & 1ull);
            if (lane == k) ltw = bw;
        }
        lt1[((size_t)b * NPAIR + (r >> 1)) * 64 + lane] = ltw;
    }
}

// ---------------------------------------------------------------------------
// Kernel C2 (fast path): greedy resolve, overlapped schedule, 512 threads
// (8 waves: cheaper barrier than 16). Per iteration p (one barrier):
//   wave 0 : joint 128-box ballot fixpoint for pair p; sup plain-ORs to
//            words 2p,2p+1 (sole writer); near d2/d3 commits (4 atomics);
//            kept_s write; prefetch of pair p+1's 7 bands.
//   wave 1 : near d4/d5 commits for pair p-1 (targets 2p+2,2p+3 -- disjoint
//            from wave 0's words; complete before word 2p+2 is read at p+1),
//            from its own band registers; then df worker duties.
//   waves1-7: df worker phase for pair p-1 (klist, commit df issued at p-1
//            for pair p-2 [targets >= 2p+2], issue far loads [>= 2(p-1)+6],
//            56-slot capacity + overflow loop).
// + fused output tail.
// ---------------------------------------------------------------------------
static __device__ __forceinline__ void bar_sync()
{
    asm volatile("s_waitcnt lgkmcnt(0)" ::: "memory");
    __builtin_amdgcn_s_barrier();
    asm volatile("" ::: "memory");
}

static __device__ __forceinline__ u64 rfl64(u64 x)
{
    uint32_t lo = __builtin_amdgcn_readfirstlane((uint32_t)x);
    uint32_t hi = __builtin_amdgcn_readfirstlane((uint32_t)(x >> 32));
    return ((u64)hi << 32) | (u64)lo;
}

__global__ void __launch_bounds__(512) resolve_kernel(const u64* __restrict__ mask,
                                                      const u64* __restrict__ ldiag,
                                                      const u64* __restrict__ s1diag,
                                                      const u64* __restrict__ s2diag,
                                                      const u64* __restrict__ s3diag,
                                                      const u64* __restrict__ s4diag,
                                                      const u64* __restrict__ s5diag,
                                                      const u64* __restrict__ lt1,
                                                      const float4* __restrict__ sboxes,
                                                      const float* __restrict__ sscore,
                                                      const int* __restrict__ scls,
                                                      const uint32_t* __restrict__ ssv,
                                                      u64* __restrict__ rem_out,
                                                      float* __restrict__ out)
{
    int b = blockIdx.x;
    int tid = threadIdx.x;
    int lane = tid & 63;
    int wv = tid >> 6;                           // 0..7
    const u64* M   = mask   + (size_t)b * NTOT * NW64;
    const u64* LD  = ldiag  + (size_t)b * NW64 * 64;
    const u64* S1A = s1diag + (size_t)b * NW64 * 64;
    const u64* S2A = s2diag + (size_t)b * NW64 * 64;
    const u64* S3A = s3diag + (size_t)b * NW64 * 64;
    const u64* S4A = s4diag + (size_t)b * NW64 * 64;
    const u64* S5A = s5diag + (size_t)b * NW64 * 64;
    const u64* LT  = lt1    + (size_t)b * NPAIR * 64;

    __shared__ u64 rem_s[NW64 + 1];              // +1: word index 167 (pair tail)
    __shared__ u64 v_s[NW64 + 1];                // v_s[167] = 0 -> alive1 = 0
    __shared__ u64 kept_s[2][2];                 // parity double-buffered
    __shared__ int klist[2][128];

    for (int t = tid; t < NW64 + 1; t += 512) rem_s[t] = 0ull;
    // v_s from ssv via per-wave ballots (wave wv covers words wv, wv+8, ...)
    for (int t = wv; t < NW64; t += 8) {
        int i = t * 64 + lane;
        uint32_t v = (i < NTOT) ? ssv[(size_t)b * NTOT + i] : 0u;
        u64 w = __ballot(v != 0u);
        if (lane == 0) v_s[t] = w;
    }
    if (tid == 0) {
        v_s[NW64] = 0ull;
        kept_s[0][0] = kept_s[0][1] = kept_s[1][0] = kept_s[1][1] = 0ull;
        klist[0][0] = 0; klist[1][0] = 0;
    }

    // wave 0 bands (7 u64, double-buffered via swap at section end)
    u64 ld0 = 0, ld1 = 0, lt = 0, s2_0 = 0, s3_0 = 0, s1_1 = 0, s2_1 = 0;
    // wave 1 bands for d4/d5 commits (pair p-1; init for pair 0)
    u64 b4_0 = 0, b5_0 = 0, b3_1 = 0, b4_1 = 0;
    if (wv == 0) {
        ld0 = LD[lane];      ld1 = LD[64 + lane];   lt = LT[lane];
        s2_0 = S2A[lane];    s3_0 = S3A[lane];
        s1_1 = S1A[64 + lane]; s2_1 = S2A[64 + lane];
    } else if (wv == 1) {
        b4_0 = S4A[lane];    b5_0 = S5A[lane];
        b3_1 = S3A[64 + lane]; b4_1 = S4A[64 + lane];
    }

    u64 df[8][3];                                // worker deferred far-OR payload
    #pragma unroll
    for (int t = 0; t < 8; ++t) {
        #pragma unroll
        for (int c = 0; c < 3; ++c) df[t][c] = 0ull;
    }

    bar_sync();

    for (int p = 0; p < NPAIR; ++p) {
        int par = p & 1;
        int w0 = 2 * p, w1 = 2 * p + 1;

        if (wv == 0) {
            // -------- issue next pair's band prefetch (covered by fixpoint) --
            int pn = (p + 1 < NPAIR) ? p + 1 : p;
            int i0 = 2 * pn;
            int i1 = (2 * pn + 1 < NW64) ? 2 * pn + 1 : NW64 - 1;
            u64 nld0 = LD [(size_t)i0 * 64 + lane];
            u64 nld1 = LD [(size_t)i1 * 64 + lane];
            u64 nlt  = LT [(size_t)pn * 64 + lane];
            u64 ns2_0 = S2A[(size_t)i0 * 64 + lane];
            u64 ns3_0 = S3A[(size_t)i0 * 64 + lane];
            u64 ns1_1 = S1A[(size_t)i1 * 64 + lane];
            u64 ns2_1 = S2A[(size_t)i1 * 64 + lane];

            // -------- joint 128-box fixpoint (no LDS on the chain) --------
            u64 a0 = rfl64(v_s[w0] & ~rem_s[w0]);
            u64 a1 = rfl64(v_s[w1] & ~rem_s[w1]);  // w1==167 -> pad gives 0
            u64 U0 = a0, U1 = a1, K0 = 0, K1 = 0;
            while (U0 | U1) {
                u64 UK0 = U0 | K0, UK1 = U1 | K1;
                bool in0 = (U0 >> lane) & 1;
                bool in1 = (U1 >> lane) & 1;
                u64 nk0 = __ballot(in0 && (ld0 & UK0) == 0ull);
                u64 nk1 = __ballot(in1 && ((lt & UK0) | (ld1 & UK1)) == 0ull);
                u64 nr0 = __ballot(in0 && (ld0 & K0) != 0ull);
                u64 nr1 = __ballot(in1 && ((lt & K0) | (ld1 & K1)) != 0ull);
                K0 |= nk0; K1 |= nk1;
                U0 &= ~(nk0 | nr0); U1 &= ~(nk1 | nr1);
            }

            if (lane == 0) {
                kept_s[par][0] = K0; kept_s[par][1] = K1;
                u64 sup0 = a0 & ~K0;               // wave 0 is sole writer of
                u64 sup1 = a1 & ~K1;               // words 2p,2p+1 this iter
                if (sup0) rem_s[w0] |= sup0;
                if (sup1) rem_s[w1] |= sup1;
            }
            // near d2/d3 only (d4/d5 moved to wave 1, deferred one pair)
            int w2 = w0 + 2, w3 = w0 + 3;
            bool h2 = w2 < NW64, h3 = w3 < NW64;
            if ((K0 >> lane) & 1) {
                if (h2 && s2_0) atomicOr((unsigned long long*)&rem_s[w2], (unsigned long long)s2_0);
                if (h3 && s3_0) atomicOr((unsigned long long*)&rem_s[w3], (unsigned long long)s3_0);
            }
            if ((K1 >> lane) & 1) {
                if (h2 && s1_1) atomicOr((unsigned long long*)&rem_s[w2], (unsigned long long)s1_1);
                if (h3 && s2_1) atomicOr((unsigned long long*)&rem_s[w3], (unsigned long long)s2_1);
            }
            // swap in the prefetched bands
            ld0 = nld0; ld1 = nld1; lt = nlt;
            s2_0 = ns2_0; s3_0 = ns3_0; s1_1 = ns1_1; s2_1 = ns2_1;
        } else {
            // ---------------- workers: pair p-1 phase ----------------
            int parw = par ^ 1;
            u64 k0 = kept_s[parw][0], k1 = kept_s[parw][1];
            int n0 = __popcll(k0);
            int nk = n0 + __popcll(k1);
            u64 below = (1ull << lane) - 1;
            if ((k0 >> lane) & 1) klist[parw][__popcll(k0 & below)] = lane;
            if ((k1 >> lane) & 1) klist[parw][n0 + __popcll(k1 & below)] = 64 + lane;

            // wave 1: d4/d5 near commits for pair p-1 (targets 2p+2, 2p+3;
            // disjoint from wave 0's words 2p,2p+1; complete before p+1 reads)
            if (wv == 1) {
                if (p > 0) {
                    int t2 = 2 * p + 2, t3 = 2 * p + 3;
                    bool g2 = t2 < NW64, g3 = t3 < NW64;
                    if ((k0 >> lane) & 1) {
                        if (g2 && b4_0) atomicOr((unsigned long long*)&rem_s[t2], (unsigned long long)b4_0);
                        if (g3 && b5_0) atomicOr((unsigned long long*)&rem_s[t3], (unsigned long long)b5_0);
                    }
                    if ((k1 >> lane) & 1) {
                        if (g2 && b3_1) atomicOr((unsigned long long*)&rem_s[t2], (unsigned long long)b3_1);
                        if (g3 && b4_1) atomicOr((unsigned long long*)&rem_s[t3], (unsigned long long)b4_1);
                    }
                }
                // load bands for pair p (used at iteration p+1)
                int i0 = 2 * p;
                int i1 = (2 * p + 1 < NW64) ? 2 * p + 1 : NW64 - 1;
                b4_0 = S4A[(size_t)i0 * 64 + lane];
                b5_0 = S5A[(size_t)i0 * 64 + lane];
                b3_1 = S3A[(size_t)i1 * 64 + lane];
                b4_1 = S4A[(size_t)i1 * 64 + lane];
            }

            // commit df issued at p-1 for pair p-2 (targets >= 2p+2)
            #pragma unroll
            for (int t = 0; t < 8; ++t) {
                #pragma unroll
                for (int c = 0; c < 3; ++c) {
                    if (df[t][c])
                        atomicOr((unsigned long long*)&rem_s[2 * p + 2 + (c << 6) + lane],
                                 (unsigned long long)df[t][c]);
                }
            }

            // issue far loads for pair p-1 (targets >= 2(p-1)+6), consumed at p+1
            int q = (p > 0) ? p - 1 : 0;
            int nkc = (nk < 56) ? nk : 56;
            #pragma unroll
            for (int t = 0; t < 8; ++t) {
                int s = (wv - 1) + t * 7;
                bool has = (p > 0) && (s < nkc);
                int rr = klist[parw][has ? s : 0];
                const u64* R = M + (size_t)(q * 128 + rr) * NW64;
                #pragma unroll
                for (int c = 0; c < 3; ++c) {
                    int w = 2 * q + 6 + (c << 6) + lane;
                    df[t][c] = (has && w < NW64) ? R[w] : 0ull;
                }
            }
            // rare overflow (nk > 56): immediate load + commit (targets >=
            // 2q+6 = 2p+4 -> disjoint from wave 0's reads)
            for (int base = 56; base < nk; base += 56) {
                #pragma unroll
                for (int t = 0; t < 8; ++t) {
                    int s = base + (wv - 1) + t * 7;
                    bool has = s < nk;
                    int rr = klist[parw][has ? s : 0];
                    const u64* R = M + (size_t)(q * 128 + rr) * NW64;
                    #pragma unroll
                    for (int c = 0; c < 3; ++c) {
                        int w = 2 * q + 6 + (c << 6) + lane;
                        u64 v2 = (has && w < NW64) ? R[w] : 0ull;
                        if (v2) atomicOr((unsigned long long*)&rem_s[w], (unsigned long long)v2);
                    }
                }
            }
        }

        bar_sync();                               // kept_s/rem_s coherent
    }

    // post-loop: all remaining df target words >= 2(NPAIR-2)+6 = 170 > 166,
    // so nothing is pending. rem_s is final.

    for (int t = tid; t < NW64; t += 512)
        rem_out[(size_t)b * NW64 + t] = rem_s[t];

    // ---- fused output tail (replaces out_kernel on the fast path) ----
    for (int t = tid; t < NTOT; t += 512) {
        size_t idx = (size_t)b * NTOT + t;
        float4 box = sboxes[idx];
        u64 rw = rem_s[t >> 6];
        bool keep = (ssv[idx] != 0u) && !((rw >> (t & 63)) & 1ull);
        float sc = keep ? sscore[idx] : 0.0f;
        float* d = out + idx * 6;
        d[0] = box.x; d[1] = box.y; d[2] = box.z; d[3] = box.w;
        d[4] = sc;    d[5] = (float)scls[idx];
        out[(size_t)NBATCH * NTOT * 6 + idx] = keep ? 1.0f : 0.0f;
    }
}

// ---------------------------------------------------------------------------
// Fallback (small ws): original single-block NMS. Writes u32 words into the
// same u64 rem buffer (little-endian layout makes bit positions identical).
// ---------------------------------------------------------------------------
extern __shared__ unsigned char nms_smem[];

__global__ void __launch_bounds__(1024) nms_kernel(const float4* __restrict__ sboxes,
                                                   const uint32_t* __restrict__ ssv,
                                                   const int* __restrict__ nvalid_arr,
                                                   uint32_t* __restrict__ supp_out)
{
#pragma clang fp contract(off)
    int b = blockIdx.x;
    float4*   lbox = (float4*)nms_smem;
    uint32_t* supp = (uint32_t*)(nms_smem + (size_t)LDS_CAP * 16);
    uint32_t* svb  = supp + NW32;

    int nv = nvalid_arr[b];
    const float4* gb = sboxes + (size_t)b * NTOT;
    const uint32_t* gv = ssv + (size_t)b * NTOT;

    for (int t = threadIdx.x; t < NW32; t += 1024) { supp[t] = 0u; svb[t] = 0u; }
    __syncthreads();
    for (int t = threadIdx.x; t < nv; t += 1024) {
        if (t < LDS_CAP) lbox[t] = gb[t];
        if (gv[t]) atomicOr(&svb[t >> 5], 1u << (t & 31));
    }
    __syncthreads();

    for (int i = 0; i < nv; ++i) {
        uint32_t sw = supp[i >> 5];
        if ((sw >> (i & 31)) & 1u) continue;
        uint32_t vw = svb[i >> 5];
        if (!((vw >> (i & 31)) & 1u)) continue;

        float4 bi = (i < LDS_CAP) ? lbox[i] : gb[i];
        float ax1 = bi.x, ay1 = bi.y, ax2 = bi.z, ay2 = bi.w;
        float area_i = (ax2 - ax1) * (ay2 - ay1);

        for (int j = i + 1 + (int)threadIdx.x; j < nv; j += 1024) {
            float4 bj = (j < LDS_CAP) ? lbox[j] : gb[j];
            float xx1 = fmaxf(bj.x, ax1);
            float yy1 = fmaxf(bj.y, ay1);
            float xx2 = fminf(bj.z, ax2);
            float yy2 = fminf(bj.w, ay2);
            float w = fmaxf(xx2 - xx1, 0.0f);
            float h = fmaxf(yy2 - yy1, 0.0f);
            float inter  = w * h;
            float area_j = (bj.z - bj.x) * (bj.w - bj.y);
            float iou = inter / ((area_i + area_j) - inter);
            if (iou > IOU_THR_F) atomicOr(&supp[j >> 5], 1u << (j & 31));
        }
        __syncthreads();
    }

    __syncthreads();
    // u64 layout: u32 word w of image b lives at u32-index b*(2*NW64) + w
    for (int t = threadIdx.x; t < NW32; t += 1024)
        supp_out[(size_t)b * (2 * NW64) + t] = supp[t];
}

// ---------------------------------------------------------------------------
// Kernel D (fallback path only): assemble outputs
// ---------------------------------------------------------------------------
__global__ void out_kernel(const float4* __restrict__ sboxes, const float* __restrict__ sscore,
                           const int* __restrict__ scls, const uint32_t* __restrict__ ssv,
                           const u64* __restrict__ rem, float* __restrict__ out)
{
    int idx = blockIdx.x * 256 + threadIdx.x;
    if (idx >= NBATCH * NTOT) return;
    int b = idx / NTOT;
    int p = idx - b * NTOT;

    float4 box = sboxes[idx];
    u64 rw = rem[(size_t)b * NW64 + (p >> 6)];
    bool keep = (ssv[idx] != 0u) && !((rw >> (p & 63)) & 1ull);
    float sc = keep ? sscore[idx] : 0.0f;

    float* d = out + (size_t)idx * 6;
    d[0] = box.x; d[1] = box.y; d[2] = box.z; d[3] = box.w;
    d[4] = sc;    d[5] = (float)scls[idx];
    out[(size_t)NBATCH * NTOT * 6 + idx] = keep ? 1.0f : 0.0f;
}

// ---------------------------------------------------------------------------
extern "C" void kernel_launch(void* const* d_in, const int* in_sizes, int n_in,
                              void* d_out, int out_size, void* d_ws, size_t ws_size,
                              hipStream_t stream)
{
    const float* p3b = (const float*)d_in[0];
    const float* p3c = (const float*)d_in[1];
    const float* p3k = (const float*)d_in[2];
    const float* p4b = (const float*)d_in[3];
    const float* p4c = (const float*)d_in[4];
    const float* p4k = (const float*)d_in[5];
    const float* p5b = (const float*)d_in[6];
    const float* p5c = (const float*)d_in[7];
    const float* p5k = (const float*)d_in[8];
    float* out = (float*)d_out;

    // workspace carve-up (256B aligned slabs)
    char* ws = (char*)d_ws;
    size_t off = 0;
    auto alloc = [&](size_t bytes) { size_t o = off; off += (bytes + 255) & ~(size_t)255; return o; };
    const size_t BN = (size_t)NBATCH * NTOT;
    uint64_t* keys      = (uint64_t*)(ws + alloc(BN * 8));
    float4*   boxes_cat = (float4*)  (ws + alloc(BN * 16));
    float*    score     = (float*)   (ws + alloc(BN * 4));
    int*      clsidx    = (int*)     (ws + alloc(BN * 4));
    uint32_t* sv        = (uint32_t*)(ws + alloc(BN * 4));
    int*      rank_arr  = (int*)     (ws + alloc(BN * 4));
    int*      inv_arr   = (int*)     (ws + alloc(BN * 4));
    float4*   sboxes    = (float4*)  (ws + alloc(BN * 16));
    float*    sscore    = (float*)   (ws + alloc(BN * 4));
    int*      scls      = (int*)     (ws + alloc(BN * 4));
    uint32_t* ssv       = (uint32_t*)(ws + alloc(BN * 4));
    u64*      rem64     = (u64*)     (ws + alloc((size_t)NBATCH * NW64 * 8));
    int*      nvalid    = (int*)     (ws + alloc(NBATCH * 4));
    u64*      ldiag     = (u64*)     (ws + alloc((size_t)NBATCH * NW64 * 64 * 8));
    u64*      s1diag    = (u64*)     (ws + alloc((size_t)NBATCH * NW64 * 64 * 8));
    u64*      s2diag    = (u64*)     (ws + alloc((size_t)NBATCH * NW64 * 64 * 8));
    u64*      s3diag    = (u64*)     (ws + alloc((size_t)NBATCH * NW64 * 64 * 8));
    u64*      s4diag    = (u64*)     (ws + alloc((size_t)NBATCH * NW64 * 64 * 8));
    u64*      s5diag    = (u64*)     (ws + alloc((size_t)NBATCH * NW64 * 64 * 8));
    u64*      lt1       = (u64*)     (ws + alloc((size_t)NBATCH * NPAIR * 64 * 8));
    u64*      mask      = (u64*)     (ws + alloc((size_t)NBATCH * NTOT * NW64 * 8));
    bool fast = (off <= ws_size);

    int nblk = (int)((BN + 255) / 256);
    prep_kernel<<<nblk, 256, 0, stream>>>(p3b, p3c, p3k, p4b, p4c, p4k, p5b, p5c, p5k,
                                          keys, boxes_cat, score, clsidx, sv,
                                          nvalid, rank_arr);

    dim3 rpgrid(RCH, RSL, NBATCH);
    rank_partial<<<rpgrid, 256, 0, stream>>>(keys, rank_arr);

    inv_kernel<<<nblk, 256, 0, stream>>>(rank_arr, inv_arr);

    gather_kernel<<<nblk, 256, 0, stream>>>(inv_arr, boxes_cat, score, clsidx, sv,
                                            sboxes, sscore, scls, ssv,
                                            nvalid, fast ? 0 : 1);

    if (fast) {
        dim3 mgrid((NW64 + 3) / 4, NW64, NBATCH);
        mask_build<<<mgrid, 256, 0, stream>>>(sboxes, mask, ldiag, s1diag, s2diag,
                                              s3diag, s4diag, s5diag, lt1);
        resolve_kernel<<<NBATCH, 512, 0, stream>>>(mask, ldiag, s1diag, s2diag, s3diag,
                                                   s4diag, s5diag, lt1,
                                                   sboxes, sscore, scls, ssv,
                                                   rem64, out);
    } else {
        hipMemsetAsync(rem64, 0, (size_t)NBATCH * NW64 * 8, stream);
        size_t smem = (size_t)LDS_CAP * 16 + (size_t)NW32 * 4 * 2;
        smem = (smem + 15) & ~(size_t)15;
        hipFuncSetAttribute((const void*)nms_kernel, hipFuncAttributeMaxDynamicSharedMemorySize, (int)smem);
        nms_kernel<<<NBATCH, 1024, smem, stream>>>(sboxes, ssv, nvalid, (uint32_t*)rem64);
        out_kernel<<<nblk, 256, 0, stream>>>(sboxes, sscore, scls, ssv, rem64, out);
    }
}

// Round 17
// 453.862 us; speedup vs baseline: 1.1208x; 1.1208x over previous
//
#include <hip/hip_runtime.h>
#include <stdint.h>

#define NB3 8112
#define NB4 2028
#define NB5 507
#define NTOT 10647           // 8112 + 2028 + 507
#define NBATCH 4
#define NCLS 20
#define NW32 333             // ceil(10647 / 32)
#define NW64 167             // ceil(10647 / 64)
#define NPAIR 84             // ceil(NW64 / 2): 128-box groups for resolve
#define NTAIL 23             // NTOT - 64*(NW64-1)
#define RCH 11               // rank: element chunks of 1024 (256 thr x 4 keys)
#define RSL 6                // rank: tile slices
#define RTP 7                // rank: 256-key tiles per slice (6*7*256 >= NTOT)
#define LDS_CAP 9984         // boxes staged in LDS (fallback kernel)
#define CONF_THR_F 0.1f
#define IOU_THR_F 0.45f
// Upper midpoint of 0.45f: RN(x) > 0.45f  <=>  x > IOU_MID (0.45f mantissa LSB
// is even -> tie at the midpoint rounds DOWN). 25-bit m x 24-bit union is
// exact in f64, so (double)inter > IOU_MID*(double)union is bit-equivalent to
// the reference's f32-divide-then-compare.
#define IOU_MID ((double)IOU_THR_F + 0x1p-26)

typedef unsigned long long u64;

// ---------------------------------------------------------------------------
// Kernel A: per-box score / class argmax / sort key.
// Also zeroes nvalid/rank (folds memsets).
// ---------------------------------------------------------------------------
__global__ void prep_kernel(const float* __restrict__ p3b, const float* __restrict__ p3c, const float* __restrict__ p3k,
                            const float* __restrict__ p4b, const float* __restrict__ p4c, const float* __restrict__ p4k,
                            const float* __restrict__ p5b, const float* __restrict__ p5c, const float* __restrict__ p5k,
                            uint64_t* __restrict__ keys, float4* __restrict__ boxes_cat,
                            float* __restrict__ score, int* __restrict__ clsidx, uint32_t* __restrict__ svout,
                            int* __restrict__ nvalid, int* __restrict__ rank)
{
#pragma clang fp contract(off)
    int idx = blockIdx.x * 256 + threadIdx.x;
    if (idx < NBATCH) nvalid[idx] = 0;
    if (idx >= NBATCH * NTOT) return;
    rank[idx] = 0;
    int b = idx / NTOT;
    int i = idx - b * NTOT;

    const float* bx; const float* cf; const float* cl; int n, off;
    if (i < NB3)            { bx = p3b; cf = p3c; cl = p3k; n = NB3; off = i; }
    else if (i < NB3 + NB4) { bx = p4b; cf = p4c; cl = p4k; n = NB4; off = i - NB3; }
    else                    { bx = p5b; cf = p5c; cl = p5k; n = NB5; off = i - NB3 - NB4; }

    size_t e = (size_t)b * n + off;
    float4 box = *(const float4*)(bx + e * 4);
    float conf = cf[e];
    const float* c = cl + e * NCLS;
    float m = c[0]; int mi = 0;
    #pragma unroll
    for (int k = 1; k < NCLS; ++k) { float v = c[k]; if (v > m) { m = v; mi = k; } }

    bool valid = conf > CONF_THR_F;
    float s = valid ? conf * m : 0.0f;           // exact: single f32 mul, no fma
    uint32_t sb = __float_as_uint(s);            // s >= 0 -> bits monotonic
    keys[idx]      = ((uint64_t)sb << 32) | (uint32_t)(0xFFFFFFFFu - (uint32_t)i);
    boxes_cat[idx] = box;
    score[idx]     = s;
    clsidx[idx]    = mi;
    svout[idx]     = valid ? 1u : 0u;
}

// ---------------------------------------------------------------------------
// Kernel B1: 2D-decomposed partial rank (proven R13/R14; vectorized tile).
// ---------------------------------------------------------------------------
__global__ void __launch_bounds__(256) rank_partial(const uint64_t* __restrict__ keys,
                                                    int* __restrict__ rank)
{
    int b = blockIdx.z;
    const uint64_t* kb = keys + (size_t)b * NTOT;
    int i0 = blockIdx.x * 1024 + threadIdx.x;
    uint64_t k0 = (i0       < NTOT) ? kb[i0]       : 0ull;
    uint64_t k1 = (i0 + 256 < NTOT) ? kb[i0 + 256] : 0ull;
    uint64_t k2 = (i0 + 512 < NTOT) ? kb[i0 + 512] : 0ull;
    uint64_t k3 = (i0 + 768 < NTOT) ? kb[i0 + 768] : 0ull;
    int r0 = 0, r1 = 0, r2 = 0, r3 = 0;

    __shared__ ulonglong2 tile2[128];
    uint64_t* tile = (uint64_t*)tile2;
    for (int tt = 0; tt < RTP; ++tt) {
        int j = (blockIdx.y * RTP + tt) * 256 + threadIdx.x;
        tile[threadIdx.x] = (j < NTOT) ? kb[j] : 0ull;   // 0 never > any real key
        __syncthreads();
        #pragma unroll 4
        for (int t = 0; t < 128; ++t) {
            ulonglong2 kt = tile2[t];
            r0 += ((kt.x > k0) ? 1 : 0) + ((kt.y > k0) ? 1 : 0);
            r1 += ((kt.x > k1) ? 1 : 0) + ((kt.y > k1) ? 1 : 0);
            r2 += ((kt.x > k2) ? 1 : 0) + ((kt.y > k2) ? 1 : 0);
            r3 += ((kt.x > k3) ? 1 : 0) + ((kt.y > k3) ? 1 : 0);
        }
        __syncthreads();
    }

    int* rb = rank + (size_t)b * NTOT;
    if (i0       < NTOT) atomicAdd(&rb[i0],       r0);
    if (i0 + 256 < NTOT) atomicAdd(&rb[i0 + 256], r1);
    if (i0 + 512 < NTOT) atomicAdd(&rb[i0 + 512], r2);
    if (i0 + 768 < NTOT) atomicAdd(&rb[i0 + 768], r3);
}

// ---------------------------------------------------------------------------
// Kernel B2: invert the permutation (proven R14). 4B scattered store only.
// inv[rk] = original index; sorted[j] == orig[inv[j]] by construction.
// ---------------------------------------------------------------------------
__global__ void inv_kernel(const int* __restrict__ rank, int* __restrict__ inv)
{
    int idx = blockIdx.x * 256 + threadIdx.x;
    if (idx >= NBATCH * NTOT) return;
    int b = idx / NTOT;
    int i = idx - b * NTOT;
    inv[(size_t)b * NTOT + rank[idx]] = i;
}

// ---------------------------------------------------------------------------
// Kernel B3 (FALLBACK PATH ONLY): materialize sorted arrays + nvalid.
// Fast path consumes boxes/scores through inv directly (no copy needed).
// ---------------------------------------------------------------------------
__global__ void gather_kernel(const int* __restrict__ inv,
                              const float4* __restrict__ boxes_cat,
                              const float* __restrict__ score,
                              const int* __restrict__ clsidx,
                              const uint32_t* __restrict__ sv,
                              float4* __restrict__ sboxes, float* __restrict__ sscore,
                              int* __restrict__ scls, uint32_t* __restrict__ ssv,
                              int* __restrict__ nvalid)
{
    int idx = blockIdx.x * 256 + threadIdx.x;
    if (idx >= NBATCH * NTOT) return;
    int b = idx / NTOT;
    int i = idx - b * NTOT;
    size_t base = (size_t)b * NTOT;
    int src = inv[idx];
    float4 box = boxes_cat[base + src];
    uint32_t v = sv[base + src];
    sboxes[idx] = box;
    sscore[idx] = score[base + src];
    scls[idx]   = clsidx[base + src];
    ssv[idx]    = v;
    int mv = v ? (i + 1) : 0;
    #pragma unroll
    for (int d = 32; d >= 1; d >>= 1) {
        int o = __shfl_xor(mv, d, 64);
        mv = (o > mv) ? o : mv;
    }
    if ((threadIdx.x & 63) == 0 && mv > 0) atomicMax(&nvalid[b], mv);
}

// ---------------------------------------------------------------------------
// Kernel C1 (fast path): build suppression bit-matrix + band buffers,
// reading boxes through the inv permutation (sorted[j] = boxes_cat[inv[j]]
// -- bit-identical to materialized sorted arrays; inv loads are L2-resident
// and outside the 64-iteration FP loop).
// IoU predicate via exact f64 midpoint comparison (see IOU_MID).
// mask[(b*NTOT + i)*NW64 + c]: bit k set iff hit && c*64+k > i && c*64+k < NTOT.
// ldiag [(b*NW64+r)*64+lane] = raw hit row & ((1<<lane)-1).
// s1..s5diag[(b*NW64+r)*64+lane] = mask word at column r+1..r+5.
// lt1[(b*NPAIR+p)*64+lane] = transpose of the (r=2p, c=2p+1) block (bit-
// symmetric hit predicate) for the joint 128-box fixpoint.
// ---------------------------------------------------------------------------
__global__ void __launch_bounds__(256) mask_build(const int* __restrict__ inv,
                                                  const float4* __restrict__ boxes_cat,
                                                  u64* __restrict__ mask,
                                                  u64* __restrict__ ldiag,
                                                  u64* __restrict__ s1diag,
                                                  u64* __restrict__ s2diag,
                                                  u64* __restrict__ s3diag,
                                                  u64* __restrict__ s4diag,
                                                  u64* __restrict__ s5diag,
                                                  u64* __restrict__ lt1)
{
#pragma clang fp contract(off)
    int c = blockIdx.y;
    if (c < blockIdx.x * 4) return;              // whole block below diagonal
    int b = blockIdx.z;
    int sub = threadIdx.x >> 6;
    int lane = threadIdx.x & 63;
    int r = blockIdx.x * 4 + sub;
    size_t base = (size_t)b * NTOT;

    __shared__ float4 cb[64];
    __shared__ float  ca[64];
    if (threadIdx.x < 64) {
        int j = c * 64 + threadIdx.x;
        int sj = inv[base + (j < NTOT ? j : NTOT - 1)];
        float4 bj = boxes_cat[base + sj];
        cb[threadIdx.x] = bj;
        ca[threadIdx.x] = (bj.z - bj.x) * (bj.w - bj.y);
    }
    __syncthreads();

    if (r >= NW64 || c < r) return;              // wave below diagonal / OOB
    int i = r * 64 + lane;
    bool live = (i < NTOT);
    int si = inv[base + (live ? i : NTOT - 1)];
    float4 bi = boxes_cat[base + si];
    float ax1 = bi.x, ay1 = bi.y, ax2 = bi.z, ay2 = bi.w;
    float area_i = (ax2 - ax1) * (ay2 - ay1);

    u64 hh = 0;
    #pragma unroll 8
    for (int k = 0; k < 64; ++k) {
        float4 bj = cb[k];
        float xx1 = fmaxf(bj.x, ax1);
        float yy1 = fmaxf(bj.y, ay1);
        float xx2 = fminf(bj.z, ax2);
        float yy2 = fminf(bj.w, ay2);
        float w = fmaxf(xx2 - xx1, 0.0f);
        float h = fmaxf(yy2 - yy1, 0.0f);
        float inter = w * h;
        float uni = (area_i + ca[k]) - inter;    // same f32 ops as reference
        bool hit = (double)inter > IOU_MID * (double)uni;   // == RN(inter/uni) > 0.45f
        hh |= (u64)hit << k;
    }

    u64 colmask = (c == NW64 - 1) ? ((1ull << NTAIL) - 1) : ~0ull;
    u64 mw = hh & colmask;

    if (live) {
        size_t bl = ((size_t)b * NW64 + r) * 64 + lane;
        if (c == r) {
            u64 gtmask = (lane < 63) ? (~0ull << (lane + 1)) : 0ull;
            mask[(base + i) * NW64 + c] = mw & gtmask;
            ldiag[bl] = hh & ((1ull << lane) - 1);
        } else {
            mask[(base + i) * NW64 + c] = mw;
            if (c == r + 1) s1diag[bl] = mw;
            if (c == r + 2) s2diag[bl] = mw;
            if (c == r + 3) s3diag[bl] = mw;
            if (c == r + 4) s4diag[bl] = mw;
            if (c == r + 5) s5diag[bl] = mw;
        }
    }
    // transposed band for the joint pair fixpoint (even r, c = r+1 only).
    if (c == r + 1 && (r & 1) == 0) {
        u64 ltw = 0;
        #pragma unroll 8
        for (int k = 0; k < 64; ++k) {
            u64 bw = __ballot((mw >> k) & 1ull);
            if (lane == k) ltw = bw;
        }
        lt1[((size_t)b * NPAIR + (r >> 1)) * 64 + lane] = ltw;
    }
}

// ---------------------------------------------------------------------------
// Kernel C2 (fast path): greedy resolve -- the proven R15 1024-thread
// balanced schedule (joint 128-box ballot fixpoint on wave 0; 15 worker
// waves with 75-slot df far-OR pipeline; one barrier per pair), with sorted
// data consumed through inv (v_s ballot build + fused output tail gather).
// ---------------------------------------------------------------------------
static __device__ __forceinline__ void bar_sync()
{
    asm volatile("s_waitcnt lgkmcnt(0)" ::: "memory");
    __builtin_amdgcn_s_barrier();
    asm volatile("" ::: "memory");
}

static __device__ __forceinline__ u64 rfl64(u64 x)
{
    uint32_t lo = __builtin_amdgcn_readfirstlane((uint32_t)x);
    uint32_t hi = __builtin_amdgcn_readfirstlane((uint32_t)(x >> 32));
    return ((u64)hi << 32) | (u64)lo;
}

__global__ void __launch_bounds__(1024) resolve_kernel(const u64* __restrict__ mask,
                                                       const u64* __restrict__ ldiag,
                                                       const u64* __restrict__ s1diag,
                                                       const u64* __restrict__ s2diag,
                                                       const u64* __restrict__ s3diag,
                                                       const u64* __restrict__ s4diag,
                                                       const u64* __restrict__ s5diag,
                                                       const u64* __restrict__ lt1,
                                                       const int* __restrict__ inv,
                                                       const float4* __restrict__ boxes_cat,
                                                       const float* __restrict__ score,
                                                       const int* __restrict__ clsidx,
                                                       const uint32_t* __restrict__ sv,
                                                       u64* __restrict__ rem_out,
                                                       float* __restrict__ out)
{
    int b = blockIdx.x;
    int tid = threadIdx.x;
    int lane = tid & 63;
    int wv = tid >> 6;
    size_t base = (size_t)b * NTOT;
    const u64* M   = mask   + base * NW64;
    const u64* LD  = ldiag  + (size_t)b * NW64 * 64;
    const u64* S1A = s1diag + (size_t)b * NW64 * 64;
    const u64* S2A = s2diag + (size_t)b * NW64 * 64;
    const u64* S3A = s3diag + (size_t)b * NW64 * 64;
    const u64* S4A = s4diag + (size_t)b * NW64 * 64;
    const u64* S5A = s5diag + (size_t)b * NW64 * 64;
    const u64* LT  = lt1    + (size_t)b * NPAIR * 64;

    __shared__ u64 rem_s[NW64 + 1];              // +1: word index 167 (pair tail)
    __shared__ u64 v_s[NW64 + 1];                // v_s[167] = 0 -> alive1 = 0
    __shared__ u64 kept_s[2][2];                 // parity double-buffered
    __shared__ int klist[2][128];

    for (int t = tid; t < NW64 + 1; t += 1024) rem_s[t] = 0ull;
    // v_s from sv via inv indirection + per-wave ballots
    for (int t = wv; t < NW64; t += 16) {
        int i = t * 64 + lane;
        uint32_t v = 0u;
        if (i < NTOT) v = sv[base + inv[base + i]];
        u64 w = __ballot(v != 0u);
        if (lane == 0) v_s[t] = w;
    }
    if (tid == 0) {
        v_s[NW64] = 0ull;
        kept_s[0][0] = kept_s[0][1] = kept_s[1][0] = kept_s[1][1] = 0ull;
        klist[0][0] = 0; klist[1][0] = 0;
    }

    // wave 0's register bands for pair 0 (11 u64, double-buffered via swap)
    u64 ld0 = 0, ld1 = 0, lt = 0;
    u64 s2_0 = 0, s3_0 = 0, s4_0 = 0, s5_0 = 0;
    u64 s1_1 = 0, s2_1 = 0, s3_1 = 0, s4_1 = 0;
    if (wv == 0) {
        ld0 = LD[lane];      ld1 = LD[64 + lane];   lt = LT[lane];
        s2_0 = S2A[lane]; s3_0 = S3A[lane]; s4_0 = S4A[lane]; s5_0 = S5A[lane];
        s1_1 = S1A[64 + lane]; s2_1 = S2A[64 + lane];
        s3_1 = S3A[64 + lane]; s4_1 = S4A[64 + lane];
    }

    u64 df[5][3];                                // worker deferred far-OR payload
    #pragma unroll
    for (int t = 0; t < 5; ++t) {
        #pragma unroll
        for (int c = 0; c < 3; ++c) df[t][c] = 0ull;
    }

    bar_sync();

    for (int p = 0; p < NPAIR; ++p) {
        int par = p & 1;
        int w0 = 2 * p, w1 = 2 * p + 1;

        if (wv == 0) {
            // -------- issue next pair's band prefetch (covered by fixpoint) --
            int pn = (p + 1 < NPAIR) ? p + 1 : p;
            int i0 = 2 * pn;
            int i1 = (2 * pn + 1 < NW64) ? 2 * pn + 1 : NW64 - 1;
            u64 nld0 = LD [(size_t)i0 * 64 + lane];
            u64 nld1 = LD [(size_t)i1 * 64 + lane];
            u64 nlt  = LT [(size_t)pn * 64 + lane];
            u64 ns2_0 = S2A[(size_t)i0 * 64 + lane];
            u64 ns3_0 = S3A[(size_t)i0 * 64 + lane];
            u64 ns4_0 = S4A[(size_t)i0 * 64 + lane];
            u64 ns5_0 = S5A[(size_t)i0 * 64 + lane];
            u64 ns1_1 = S1A[(size_t)i1 * 64 + lane];
            u64 ns2_1 = S2A[(size_t)i1 * 64 + lane];
            u64 ns3_1 = S3A[(size_t)i1 * 64 + lane];
            u64 ns4_1 = S4A[(size_t)i1 * 64 + lane];

            // -------- joint 128-box fixpoint (no LDS on the chain) --------
            u64 a0 = rfl64(v_s[w0] & ~rem_s[w0]);
            u64 a1 = rfl64(v_s[w1] & ~rem_s[w1]);  // w1==167 -> pad gives 0
            u64 U0 = a0, U1 = a1, K0 = 0, K1 = 0;
            while (U0 | U1) {
                u64 UK0 = U0 | K0, UK1 = U1 | K1;
                bool in0 = (U0 >> lane) & 1;
                bool in1 = (U1 >> lane) & 1;
                u64 nk0 = __ballot(in0 && (ld0 & UK0) == 0ull);
                u64 nk1 = __ballot(in1 && ((lt & UK0) | (ld1 & UK1)) == 0ull);
                u64 nr0 = __ballot(in0 && (ld0 & K0) != 0ull);
                u64 nr1 = __ballot(in1 && ((lt & K0) | (ld1 & K1)) != 0ull);
                K0 |= nk0; K1 |= nk1;
                U0 &= ~(nk0 | nr0); U1 &= ~(nk1 | nr1);
            }

            if (lane == 0) {
                kept_s[par][0] = K0; kept_s[par][1] = K1;
                u64 sup0 = a0 & ~K0;               // wave 0 is sole writer of
                u64 sup1 = a1 & ~K1;               // words 2p,2p+1 this iter
                if (sup0) rem_s[w0] |= sup0;
                if (sup1) rem_s[w1] |= sup1;
            }
            // near words 2p+2..2p+5 from register bands (guard by TARGET index)
            int w2 = w0 + 2, w3 = w0 + 3, w4 = w0 + 4, w5 = w0 + 5;
            bool h2 = w2 < NW64, h3 = w3 < NW64, h4 = w4 < NW64, h5 = w5 < NW64;
            if ((K0 >> lane) & 1) {
                if (h2 && s2_0) atomicOr((unsigned long long*)&rem_s[w2], (unsigned long long)s2_0);
                if (h3 && s3_0) atomicOr((unsigned long long*)&rem_s[w3], (unsigned long long)s3_0);
                if (h4 && s4_0) atomicOr((unsigned long long*)&rem_s[w4], (unsigned long long)s4_0);
                if (h5 && s5_0) atomicOr((unsigned long long*)&rem_s[w5], (unsigned long long)s5_0);
            }
            if ((K1 >> lane) & 1) {
                if (h2 && s1_1) atomicOr((unsigned long long*)&rem_s[w2], (unsigned long long)s1_1);
                if (h3 && s2_1) atomicOr((unsigned long long*)&rem_s[w3], (unsigned long long)s2_1);
                if (h4 && s3_1) atomicOr((unsigned long long*)&rem_s[w4], (unsigned long long)s3_1);
                if (h5 && s4_1) atomicOr((unsigned long long*)&rem_s[w5], (unsigned long long)s4_1);
            }
            // swap in the prefetched bands (waitcnt lands here, fully covered)
            ld0 = nld0; ld1 = nld1; lt = nlt;
            s2_0 = ns2_0; s3_0 = ns3_0; s4_0 = ns4_0; s5_0 = ns5_0;
            s1_1 = ns1_1; s2_1 = ns2_1; s3_1 = ns3_1; s4_1 = ns4_1;
        } else {
            // ---------------- workers: pair p-1 phase ----------------
            int parw = par ^ 1;
            u64 k0 = kept_s[parw][0], k1 = kept_s[parw][1];
            int n0 = __popcll(k0);
            int nk = n0 + __popcll(k1);
            u64 below = (1ull << lane) - 1;
            if ((k0 >> lane) & 1) klist[parw][__popcll(k0 & below)] = lane;
            if ((k1 >> lane) & 1) klist[parw][n0 + __popcll(k1 & below)] = 64 + lane;

            // commit df issued at p-1 for pair p-2 (targets >= 2p+2; wave 0
            // reads 2p,2p+1 concurrently -> disjoint)
            #pragma unroll
            for (int t = 0; t < 5; ++t) {
                #pragma unroll
                for (int c = 0; c < 3; ++c) {
                    if (df[t][c])
                        atomicOr((unsigned long long*)&rem_s[2 * p + 2 + (c << 6) + lane],
                                 (unsigned long long)df[t][c]);
                }
            }

            // issue far loads for pair p-1 (targets >= 2(p-1)+6), consumed at p+1
            int q = (p > 0) ? p - 1 : 0;
            int nkc = (nk < 64) ? nk : 64;
            #pragma unroll
            for (int t = 0; t < 5; ++t) {
                int s = (wv - 1) + t * 15;
                bool has = (p > 0) && (s < nkc);
                int rr = klist[parw][has ? s : 0];
                const u64* R = M + (size_t)(q * 128 + rr) * NW64;
                #pragma unroll
                for (int c = 0; c < 3; ++c) {
                    int w = 2 * q + 6 + (c << 6) + lane;
                    df[t][c] = (has && w < NW64) ? R[w] : 0ull;
                }
            }
            // rare overflow (nk > 64): immediate load + commit (targets >=
            // 2q+6 = 2p+4 -> disjoint from wave 0's reads)
            for (int bs = 64; bs < nk; bs += 64) {
                #pragma unroll
                for (int t = 0; t < 5; ++t) {
                    int s = bs + (wv - 1) + t * 15;
                    bool has = s < nk;
                    int rr = klist[parw][has ? s : 0];
                    const u64* R = M + (size_t)(q * 128 + rr) * NW64;
                    #pragma unroll
                    for (int c = 0; c < 3; ++c) {
                        int w = 2 * q + 6 + (c << 6) + lane;
                        u64 v2 = (has && w < NW64) ? R[w] : 0ull;
                        if (v2) atomicOr((unsigned long long*)&rem_s[w], (unsigned long long)v2);
                    }
                }
            }
        }

        bar_sync();                               // kept_s/rem_s coherent
    }

    // post-loop: all remaining df target words >= 2(NPAIR-2)+6 = 170 > 166,
    // so nothing is pending. rem_s is final.

    for (int t = tid; t < NW64; t += 1024)
        rem_out[(size_t)b * NW64 + t] = rem_s[t];

    // ---- fused output tail: gather through inv (L2-resident random reads,
    // coalesced writes; replaces out_kernel AND gather_kernel on fast path) --
    for (int t = tid; t < NTOT; t += 1024) {
        int src = inv[base + t];
        float4 box = boxes_cat[base + src];
        uint32_t v = sv[base + src];
        u64 rw = rem_s[t >> 6];
        bool keep = (v != 0u) && !((rw >> (t & 63)) & 1ull);
        float sc = keep ? score[base + src] : 0.0f;
        float* d = out + (base + t) * 6;
        d[0] = box.x; d[1] = box.y; d[2] = box.z; d[3] = box.w;
        d[4] = sc;    d[5] = (float)clsidx[base + src];
        out[(size_t)NBATCH * NTOT * 6 + base + t] = keep ? 1.0f : 0.0f;
    }
}

// ---------------------------------------------------------------------------
// Fallback (small ws): original single-block NMS. Writes u32 words into the
// same u64 rem buffer (little-endian layout makes bit positions identical).
// ---------------------------------------------------------------------------
extern __shared__ unsigned char nms_smem[];

__global__ void __launch_bounds__(1024) nms_kernel(const float4* __restrict__ sboxes,
                                                   const uint32_t* __restrict__ ssv,
                                                   const int* __restrict__ nvalid_arr,
                                                   uint32_t* __restrict__ supp_out)
{
#pragma clang fp contract(off)
    int b = blockIdx.x;
    float4*   lbox = (float4*)nms_smem;
    uint32_t* supp = (uint32_t*)(nms_smem + (size_t)LDS_CAP * 16);
    uint32_t* svb  = supp + NW32;

    int nv = nvalid_arr[b];
    const float4* gb = sboxes + (size_t)b * NTOT;
    const uint32_t* gv = ssv + (size_t)b * NTOT;

    for (int t = threadIdx.x; t < NW32; t += 1024) { supp[t] = 0u; svb[t] = 0u; }
    __syncthreads();
    for (int t = threadIdx.x; t < nv; t += 1024) {
        if (t < LDS_CAP) lbox[t] = gb[t];
        if (gv[t]) atomicOr(&svb[t >> 5], 1u << (t & 31));
    }
    __syncthreads();

    for (int i = 0; i < nv; ++i) {
        uint32_t sw = supp[i >> 5];
        if ((sw >> (i & 31)) & 1u) continue;
        uint32_t vw = svb[i >> 5];
        if (!((vw >> (i & 31)) & 1u)) continue;

        float4 bi = (i < LDS_CAP) ? lbox[i] : gb[i];
        float ax1 = bi.x, ay1 = bi.y, ax2 = bi.z, ay2 = bi.w;
        float area_i = (ax2 - ax1) * (ay2 - ay1);

        for (int j = i + 1 + (int)threadIdx.x; j < nv; j += 1024) {
            float4 bj = (j < LDS_CAP) ? lbox[j] : gb[j];
            float xx1 = fmaxf(bj.x, ax1);
            float yy1 = fmaxf(bj.y, ay1);
            float xx2 = fminf(bj.z, ax2);
            float yy2 = fminf(bj.w, ay2);
            float w = fmaxf(xx2 - xx1, 0.0f);
            float h = fmaxf(yy2 - yy1, 0.0f);
            float inter  = w * h;
            float area_j = (bj.z - bj.x) * (bj.w - bj.y);
            float iou = inter / ((area_i + area_j) - inter);
            if (iou > IOU_THR_F) atomicOr(&supp[j >> 5], 1u << (j & 31));
        }
        __syncthreads();
    }

    __syncthreads();
    // u64 layout: u32 word w of image b lives at u32-index b*(2*NW64) + w
    for (int t = threadIdx.x; t < NW32; t += 1024)
        supp_out[(size_t)b * (2 * NW64) + t] = supp[t];
}

// ---------------------------------------------------------------------------
// Kernel D (fallback path only): assemble outputs
// ---------------------------------------------------------------------------
__global__ void out_kernel(const float4* __restrict__ sboxes, const float* __restrict__ sscore,
                           const int* __restrict__ scls, const uint32_t* __restrict__ ssv,
                           const u64* __restrict__ rem, float* __restrict__ out)
{
    int idx = blockIdx.x * 256 + threadIdx.x;
    if (idx >= NBATCH * NTOT) return;
    int b = idx / NTOT;
    int p = idx - b * NTOT;

    float4 box = sboxes[idx];
    u64 rw = rem[(size_t)b * NW64 + (p >> 6)];
    bool keep = (ssv[idx] != 0u) && !((rw >> (p & 63)) & 1ull);
    float sc = keep ? sscore[idx] : 0.0f;

    float* d = out + (size_t)idx * 6;
    d[0] = box.x; d[1] = box.y; d[2] = box.z; d[3] = box.w;
    d[4] = sc;    d[5] = (float)scls[idx];
    out[(size_t)NBATCH * NTOT * 6 + idx] = keep ? 1.0f : 0.0f;
}

// ---------------------------------------------------------------------------
extern "C" void kernel_launch(void* const* d_in, const int* in_sizes, int n_in,
                              void* d_out, int out_size, void* d_ws, size_t ws_size,
                              hipStream_t stream)
{
    const float* p3b = (const float*)d_in[0];
    const float* p3c = (const float*)d_in[1];
    const float* p3k = (const float*)d_in[2];
    const float* p4b = (const float*)d_in[3];
    const float* p4c = (const float*)d_in[4];
    const float* p4k = (const float*)d_in[5];
    const float* p5b = (const float*)d_in[6];
    const float* p5c = (const float*)d_in[7];
    const float* p5k = (const float*)d_in[8];
    float* out = (float*)d_out;

    // workspace carve-up (256B aligned slabs)
    char* ws = (char*)d_ws;
    size_t off = 0;
    auto alloc = [&](size_t bytes) { size_t o = off; off += (bytes + 255) & ~(size_t)255; return o; };
    const size_t BN = (size_t)NBATCH * NTOT;
    uint64_t* keys      = (uint64_t*)(ws + alloc(BN * 8));
    float4*   boxes_cat = (float4*)  (ws + alloc(BN * 16));
    float*    score     = (float*)   (ws + alloc(BN * 4));
    int*      clsidx    = (int*)     (ws + alloc(BN * 4));
    uint32_t* sv        = (uint32_t*)(ws + alloc(BN * 4));
    int*      rank_arr  = (int*)     (ws + alloc(BN * 4));
    int*      inv_arr   = (int*)     (ws + alloc(BN * 4));
    float4*   sboxes    = (float4*)  (ws + alloc(BN * 16));
    float*    sscore    = (float*)   (ws + alloc(BN * 4));
    int*      scls      = (int*)     (ws + alloc(BN * 4));
    uint32_t* ssv       = (uint32_t*)(ws + alloc(BN * 4));
    u64*      rem64     = (u64*)     (ws + alloc((size_t)NBATCH * NW64 * 8));
    int*      nvalid    = (int*)     (ws + alloc(NBATCH * 4));
    u64*      ldiag     = (u64*)     (ws + alloc((size_t)NBATCH * NW64 * 64 * 8));
    u64*      s1diag    = (u64*)     (ws + alloc((size_t)NBATCH * NW64 * 64 * 8));
    u64*      s2diag    = (u64*)     (ws + alloc((size_t)NBATCH * NW64 * 64 * 8));
    u64*      s3diag    = (u64*)     (ws + alloc((size_t)NBATCH * NW64 * 64 * 8));
    u64*      s4diag    = (u64*)     (ws + alloc((size_t)NBATCH * NW64 * 64 * 8));
    u64*      s5diag    = (u64*)     (ws + alloc((size_t)NBATCH * NW64 * 64 * 8));
    u64*      lt1       = (u64*)     (ws + alloc((size_t)NBATCH * NPAIR * 64 * 8));
    u64*      mask      = (u64*)     (ws + alloc((size_t)NBATCH * NTOT * NW64 * 8));
    bool fast = (off <= ws_size);

    int nblk = (int)((BN + 255) / 256);
    prep_kernel<<<nblk, 256, 0, stream>>>(p3b, p3c, p3k, p4b, p4c, p4k, p5b, p5c, p5k,
                                          keys, boxes_cat, score, clsidx, sv,
                                          nvalid, rank_arr);

    dim3 rpgrid(RCH, RSL, NBATCH);
    rank_partial<<<rpgrid, 256, 0, stream>>>(keys, rank_arr);

    inv_kernel<<<nblk, 256, 0, stream>>>(rank_arr, inv_arr);

    if (fast) {
        dim3 mgrid((NW64 + 3) / 4, NW64, NBATCH);
        mask_build<<<mgrid, 256, 0, stream>>>(inv_arr, boxes_cat, mask, ldiag,
                                              s1diag, s2diag, s3diag, s4diag,
                                              s5diag, lt1);
        resolve_kernel<<<NBATCH, 1024, 0, stream>>>(mask, ldiag, s1diag, s2diag, s3diag,
                                                    s4diag, s5diag, lt1,
                                                    inv_arr, boxes_cat, score, clsidx, sv,
                                                    rem64, out);
    } else {
        gather_kernel<<<nblk, 256, 0, stream>>>(inv_arr, boxes_cat, score, clsidx, sv,
                                                sboxes, sscore, scls, ssv, nvalid);
        hipMemsetAsync(rem64, 0, (size_t)NBATCH * NW64 * 8, stream);
        size_t smem = (size_t)LDS_CAP * 16 + (size_t)NW32 * 4 * 2;
        smem = (smem + 15) & ~(size_t)15;
        hipFuncSetAttribute((const void*)nms_kernel, hipFuncAttributeMaxDynamicSharedMemorySize, (int)smem);
        nms_kernel<<<NBATCH, 1024, smem, stream>>>(sboxes, ssv, nvalid, (uint32_t*)rem64);
        out_kernel<<<nblk, 256, 0, stream>>>(sboxes, sscore, scls, ssv, rem64, out);
    }
}

// Round 18
// 436.942 us; speedup vs baseline: 1.1642x; 1.0387x over previous
//
#include <hip/hip_runtime.h>
#include <stdint.h>

#define NB3 8112
#define NB4 2028
#define NB5 507
#define NTOT 10647           // 8112 + 2028 + 507
#define NBATCH 4
#define NCLS 20
#define NW32 333             // ceil(10647 / 32)
#define NW64 167             // ceil(10647 / 64)
#define NPAIR 84             // ceil(NW64 / 2): 128-box groups for resolve
#define NTAIL 23             // NTOT - 64*(NW64-1)
#define RCH 11               // rank: element chunks of 1024 (256 thr x 4 keys)
#define RSL 6                // rank: tile slices
#define RTP 7                // rank: 256-key tiles per slice (6*7*256 >= NTOT)
#define LDS_CAP 9984         // boxes staged in LDS (fallback kernel)
#define CONF_THR_F 0.1f
#define IOU_THR_F 0.45f
// Upper midpoint of 0.45f: RN(x) > 0.45f  <=>  x > IOU_MID (0.45f mantissa LSB
// is even -> tie at the midpoint rounds DOWN). 25-bit m x 24-bit union is
// exact in f64, so (double)inter > IOU_MID*(double)union is bit-equivalent to
// the reference's f32-divide-then-compare.
#define IOU_MID ((double)IOU_THR_F + 0x1p-26)

typedef unsigned long long u64;

// ---------------------------------------------------------------------------
// Kernel A: per-box score / class argmax / sort key.
// Also zeroes nvalid/rank (folds memsets).
// ---------------------------------------------------------------------------
__global__ void prep_kernel(const float* __restrict__ p3b, const float* __restrict__ p3c, const float* __restrict__ p3k,
                            const float* __restrict__ p4b, const float* __restrict__ p4c, const float* __restrict__ p4k,
                            const float* __restrict__ p5b, const float* __restrict__ p5c, const float* __restrict__ p5k,
                            uint64_t* __restrict__ keys, float4* __restrict__ boxes_cat,
                            float* __restrict__ score, int* __restrict__ clsidx, uint32_t* __restrict__ svout,
                            int* __restrict__ nvalid, int* __restrict__ rank)
{
#pragma clang fp contract(off)
    int idx = blockIdx.x * 256 + threadIdx.x;
    if (idx < NBATCH) nvalid[idx] = 0;
    if (idx >= NBATCH * NTOT) return;
    rank[idx] = 0;
    int b = idx / NTOT;
    int i = idx - b * NTOT;

    const float* bx; const float* cf; const float* cl; int n, off;
    if (i < NB3)            { bx = p3b; cf = p3c; cl = p3k; n = NB3; off = i; }
    else if (i < NB3 + NB4) { bx = p4b; cf = p4c; cl = p4k; n = NB4; off = i - NB3; }
    else                    { bx = p5b; cf = p5c; cl = p5k; n = NB5; off = i - NB3 - NB4; }

    size_t e = (size_t)b * n + off;
    float4 box = *(const float4*)(bx + e * 4);
    float conf = cf[e];
    const float* c = cl + e * NCLS;
    float m = c[0]; int mi = 0;
    #pragma unroll
    for (int k = 1; k < NCLS; ++k) { float v = c[k]; if (v > m) { m = v; mi = k; } }

    bool valid = conf > CONF_THR_F;
    float s = valid ? conf * m : 0.0f;           // exact: single f32 mul, no fma
    uint32_t sb = __float_as_uint(s);            // s >= 0 -> bits monotonic
    keys[idx]      = ((uint64_t)sb << 32) | (uint32_t)(0xFFFFFFFFu - (uint32_t)i);
    boxes_cat[idx] = box;
    score[idx]     = s;
    clsidx[idx]    = mi;
    svout[idx]     = valid ? 1u : 0u;
}

// ---------------------------------------------------------------------------
// Kernel B1: 2D-decomposed partial rank (proven R13/R14; vectorized tile).
// ---------------------------------------------------------------------------
__global__ void __launch_bounds__(256) rank_partial(const uint64_t* __restrict__ keys,
                                                    int* __restrict__ rank)
{
    int b = blockIdx.z;
    const uint64_t* kb = keys + (size_t)b * NTOT;
    int i0 = blockIdx.x * 1024 + threadIdx.x;
    uint64_t k0 = (i0       < NTOT) ? kb[i0]       : 0ull;
    uint64_t k1 = (i0 + 256 < NTOT) ? kb[i0 + 256] : 0ull;
    uint64_t k2 = (i0 + 512 < NTOT) ? kb[i0 + 512] : 0ull;
    uint64_t k3 = (i0 + 768 < NTOT) ? kb[i0 + 768] : 0ull;
    int r0 = 0, r1 = 0, r2 = 0, r3 = 0;

    __shared__ ulonglong2 tile2[128];
    uint64_t* tile = (uint64_t*)tile2;
    for (int tt = 0; tt < RTP; ++tt) {
        int j = (blockIdx.y * RTP + tt) * 256 + threadIdx.x;
        tile[threadIdx.x] = (j < NTOT) ? kb[j] : 0ull;   // 0 never > any real key
        __syncthreads();
        #pragma unroll 4
        for (int t = 0; t < 128; ++t) {
            ulonglong2 kt = tile2[t];
            r0 += ((kt.x > k0) ? 1 : 0) + ((kt.y > k0) ? 1 : 0);
            r1 += ((kt.x > k1) ? 1 : 0) + ((kt.y > k1) ? 1 : 0);
            r2 += ((kt.x > k2) ? 1 : 0) + ((kt.y > k2) ? 1 : 0);
            r3 += ((kt.x > k3) ? 1 : 0) + ((kt.y > k3) ? 1 : 0);
        }
        __syncthreads();
    }

    int* rb = rank + (size_t)b * NTOT;
    if (i0       < NTOT) atomicAdd(&rb[i0],       r0);
    if (i0 + 256 < NTOT) atomicAdd(&rb[i0 + 256], r1);
    if (i0 + 512 < NTOT) atomicAdd(&rb[i0 + 512], r2);
    if (i0 + 768 < NTOT) atomicAdd(&rb[i0 + 768], r3);
}

// ---------------------------------------------------------------------------
// Kernel B2: invert the permutation (proven R14). 4B scattered store only.
// ---------------------------------------------------------------------------
__global__ void inv_kernel(const int* __restrict__ rank, int* __restrict__ inv)
{
    int idx = blockIdx.x * 256 + threadIdx.x;
    if (idx >= NBATCH * NTOT) return;
    int b = idx / NTOT;
    int i = idx - b * NTOT;
    inv[(size_t)b * NTOT + rank[idx]] = i;
}

// ---------------------------------------------------------------------------
// Kernel B3: gather into sorted arrays (proven R14). Random L2-resident reads
// + coalesced writes. nvalid only when fallback path needs it.
// ---------------------------------------------------------------------------
__global__ void gather_kernel(const int* __restrict__ inv,
                              const float4* __restrict__ boxes_cat,
                              const float* __restrict__ score,
                              const int* __restrict__ clsidx,
                              const uint32_t* __restrict__ sv,
                              float4* __restrict__ sboxes, float* __restrict__ sscore,
                              int* __restrict__ scls, uint32_t* __restrict__ ssv,
                              int* __restrict__ nvalid, int need_nvalid)
{
    int idx = blockIdx.x * 256 + threadIdx.x;
    if (idx >= NBATCH * NTOT) return;
    int b = idx / NTOT;
    int i = idx - b * NTOT;
    size_t base = (size_t)b * NTOT;
    int src = inv[idx];
    float4 box = boxes_cat[base + src];
    uint32_t v = sv[base + src];
    sboxes[idx] = box;
    sscore[idx] = score[base + src];
    scls[idx]   = clsidx[base + src];
    ssv[idx]    = v;
    if (need_nvalid) {
        int mv = v ? (i + 1) : 0;
        #pragma unroll
        for (int d = 32; d >= 1; d >>= 1) {
            int o = __shfl_xor(mv, d, 64);
            mv = (o > mv) ? o : mv;
        }
        if ((threadIdx.x & 63) == 0 && mv > 0) atomicMax(&nvalid[b], mv);
    }
}

// ---------------------------------------------------------------------------
// Kernel C1 (fast path): build suppression bit-matrix + band buffers.
// QUAD-COLUMN BLOCKED: each block = 4 row-chunks (one per wave) x 4 column
// chunks (256-box cb tile in LDS). Row boxes (bi) load once per wave and are
// reused across 4 column chunks; quad-triangular launch (by >= bx) removes
// most below-diagonal blocks. All column-chunk conditions are wave-uniform,
// so the lt1 ballot transpose remains safe. Outputs identical to R15.
// IoU predicate via exact f64 midpoint comparison (see IOU_MID).
// ---------------------------------------------------------------------------
__global__ void __launch_bounds__(256) mask_build(const float4* __restrict__ sboxes,
                                                  u64* __restrict__ mask,
                                                  u64* __restrict__ ldiag,
                                                  u64* __restrict__ s1diag,
                                                  u64* __restrict__ s2diag,
                                                  u64* __restrict__ s3diag,
                                                  u64* __restrict__ s4diag,
                                                  u64* __restrict__ s5diag,
                                                  u64* __restrict__ lt1)
{
#pragma clang fp contract(off)
    int bx = blockIdx.x;                          // rows r in [4bx, 4bx+4)
    int by = blockIdx.y;                          // cols c in [4by, 4by+4)
    if (by < bx) return;                          // below quad-diagonal
    int b = blockIdx.z;
    int sub = threadIdx.x >> 6;
    int lane = threadIdx.x & 63;
    int r = bx * 4 + sub;

    __shared__ float4 cb[256];
    __shared__ float  ca[256];
    {
        int j = by * 256 + threadIdx.x;
        float4 bj = sboxes[(size_t)b * NTOT + (j < NTOT ? j : NTOT - 1)];
        cb[threadIdx.x] = bj;
        ca[threadIdx.x] = (bj.z - bj.x) * (bj.w - bj.y);
    }
    __syncthreads();

    if (r >= NW64) return;
    int i = r * 64 + lane;
    bool live = (i < NTOT);
    float4 bi = sboxes[(size_t)b * NTOT + (live ? i : NTOT - 1)];
    float ax1 = bi.x, ay1 = bi.y, ax2 = bi.z, ay2 = bi.w;
    float area_i = (ax2 - ax1) * (ay2 - ay1);
    size_t bl = ((size_t)b * NW64 + r) * 64 + lane;

    #pragma unroll
    for (int cc = 0; cc < 4; ++cc) {
        int c = by * 4 + cc;
        if (c < r || c >= NW64) continue;         // wave-uniform

        u64 hh = 0;
        #pragma unroll 8
        for (int k = 0; k < 64; ++k) {
            float4 bj = cb[cc * 64 + k];
            float xx1 = fmaxf(bj.x, ax1);
            float yy1 = fmaxf(bj.y, ay1);
            float xx2 = fminf(bj.z, ax2);
            float yy2 = fminf(bj.w, ay2);
            float w = fmaxf(xx2 - xx1, 0.0f);
            float h = fmaxf(yy2 - yy1, 0.0f);
            float inter = w * h;
            float uni = (area_i + ca[cc * 64 + k]) - inter;   // same f32 ops as ref
            bool hit = (double)inter > IOU_MID * (double)uni; // == RN(inter/uni) > 0.45f
            hh |= (u64)hit << k;
        }

        u64 colmask = (c == NW64 - 1) ? ((1ull << NTAIL) - 1) : ~0ull;
        u64 mw = hh & colmask;

        if (live) {
            if (c == r) {
                u64 gtmask = (lane < 63) ? (~0ull << (lane + 1)) : 0ull;
                mask[((size_t)b * NTOT + i) * NW64 + c] = mw & gtmask;
                ldiag[bl] = hh & ((1ull << lane) - 1);
            } else {
                mask[((size_t)b * NTOT + i) * NW64 + c] = mw;
                if (c == r + 1) s1diag[bl] = mw;
                if (c == r + 2) s2diag[bl] = mw;
                if (c == r + 3) s3diag[bl] = mw;
                if (c == r + 4) s4diag[bl] = mw;
                if (c == r + 5) s5diag[bl] = mw;
            }
        }
        // transposed band for the joint pair fixpoint (even r, c = r+1 only)
        if (c == r + 1 && (r & 1) == 0) {
            u64 ltw = 0;
            #pragma unroll 8
            for (int k = 0; k < 64; ++k) {
                u64 bw = __ballot((mw >> k) & 1ull);
                if (lane == k) ltw = bw;
            }
            lt1[((size_t)b * NPAIR + (r >> 1)) * 64 + lane] = ltw;
        }
    }
}

// ---------------------------------------------------------------------------
// Kernel C2 (fast path): greedy resolve -- proven R15 (432us) verbatim:
// 1024 threads, overlapped schedule; wave 0 = joint 128-box ballot fixpoint
// + near-band atomics + prefetch-first double-buffered bands; waves 1-15 =
// worker df far-OR pipeline (75 slots); one barrier per pair; fused output.
// ---------------------------------------------------------------------------
static __device__ __forceinline__ void bar_sync()
{
    asm volatile("s_waitcnt lgkmcnt(0)" ::: "memory");
    __builtin_amdgcn_s_barrier();
    asm volatile("" ::: "memory");
}

static __device__ __forceinline__ u64 rfl64(u64 x)
{
    uint32_t lo = __builtin_amdgcn_readfirstlane((uint32_t)x);
    uint32_t hi = __builtin_amdgcn_readfirstlane((uint32_t)(x >> 32));
    return ((u64)hi << 32) | (u64)lo;
}

__global__ void __launch_bounds__(1024) resolve_kernel(const u64* __restrict__ mask,
                                                       const u64* __restrict__ ldiag,
                                                       const u64* __restrict__ s1diag,
                                                       const u64* __restrict__ s2diag,
                                                       const u64* __restrict__ s3diag,
                                                       const u64* __restrict__ s4diag,
                                                       const u64* __restrict__ s5diag,
                                                       const u64* __restrict__ lt1,
                                                       const float4* __restrict__ sboxes,
                                                       const float* __restrict__ sscore,
                                                       const int* __restrict__ scls,
                                                       const uint32_t* __restrict__ ssv,
                                                       u64* __restrict__ rem_out,
                                                       float* __restrict__ out)
{
    int b = blockIdx.x;
    int tid = threadIdx.x;
    int lane = tid & 63;
    int wv = tid >> 6;
    const u64* M   = mask   + (size_t)b * NTOT * NW64;
    const u64* LD  = ldiag  + (size_t)b * NW64 * 64;
    const u64* S1A = s1diag + (size_t)b * NW64 * 64;
    const u64* S2A = s2diag + (size_t)b * NW64 * 64;
    const u64* S3A = s3diag + (size_t)b * NW64 * 64;
    const u64* S4A = s4diag + (size_t)b * NW64 * 64;
    const u64* S5A = s5diag + (size_t)b * NW64 * 64;
    const u64* LT  = lt1    + (size_t)b * NPAIR * 64;

    __shared__ u64 rem_s[NW64 + 1];              // +1: word index 167 (pair tail)
    __shared__ u64 v_s[NW64 + 1];                // v_s[167] = 0 -> alive1 = 0
    __shared__ u64 kept_s[2][2];                 // parity double-buffered
    __shared__ int klist[2][128];

    for (int t = tid; t < NW64 + 1; t += 1024) rem_s[t] = 0ull;
    // v_s from ssv via per-wave ballots (wave wv covers words wv, wv+16, ...)
    for (int t = wv; t < NW64; t += 16) {
        int i = t * 64 + lane;
        uint32_t v = (i < NTOT) ? ssv[(size_t)b * NTOT + i] : 0u;
        u64 w = __ballot(v != 0u);
        if (lane == 0) v_s[t] = w;
    }
    if (tid == 0) {
        v_s[NW64] = 0ull;
        kept_s[0][0] = kept_s[0][1] = kept_s[1][0] = kept_s[1][1] = 0ull;
        klist[0][0] = 0; klist[1][0] = 0;
    }

    // wave 0's register bands for pair 0 (11 u64, double-buffered via swap)
    u64 ld0 = 0, ld1 = 0, lt = 0;
    u64 s2_0 = 0, s3_0 = 0, s4_0 = 0, s5_0 = 0;
    u64 s1_1 = 0, s2_1 = 0, s3_1 = 0, s4_1 = 0;
    if (wv == 0) {
        ld0 = LD[lane];      ld1 = LD[64 + lane];   lt = LT[lane];
        s2_0 = S2A[lane]; s3_0 = S3A[lane]; s4_0 = S4A[lane]; s5_0 = S5A[lane];
        s1_1 = S1A[64 + lane]; s2_1 = S2A[64 + lane];
        s3_1 = S3A[64 + lane]; s4_1 = S4A[64 + lane];
    }

    u64 df[5][3];                                // worker deferred far-OR payload
    #pragma unroll
    for (int t = 0; t < 5; ++t) {
        #pragma unroll
        for (int c = 0; c < 3; ++c) df[t][c] = 0ull;
    }

    bar_sync();

    for (int p = 0; p < NPAIR; ++p) {
        int par = p & 1;
        int w0 = 2 * p, w1 = 2 * p + 1;

        if (wv == 0) {
            // -------- issue next pair's band prefetch (covered by fixpoint) --
            int pn = (p + 1 < NPAIR) ? p + 1 : p;
            int i0 = 2 * pn;
            int i1 = (2 * pn + 1 < NW64) ? 2 * pn + 1 : NW64 - 1;
            u64 nld0 = LD [(size_t)i0 * 64 + lane];
            u64 nld1 = LD [(size_t)i1 * 64 + lane];
            u64 nlt  = LT [(size_t)pn * 64 + lane];
            u64 ns2_0 = S2A[(size_t)i0 * 64 + lane];
            u64 ns3_0 = S3A[(size_t)i0 * 64 + lane];
            u64 ns4_0 = S4A[(size_t)i0 * 64 + lane];
            u64 ns5_0 = S5A[(size_t)i0 * 64 + lane];
            u64 ns1_1 = S1A[(size_t)i1 * 64 + lane];
            u64 ns2_1 = S2A[(size_t)i1 * 64 + lane];
            u64 ns3_1 = S3A[(size_t)i1 * 64 + lane];
            u64 ns4_1 = S4A[(size_t)i1 * 64 + lane];

            // -------- joint 128-box fixpoint (no LDS on the chain) --------
            u64 a0 = rfl64(v_s[w0] & ~rem_s[w0]);
            u64 a1 = rfl64(v_s[w1] & ~rem_s[w1]);  // w1==167 -> pad gives 0
            u64 U0 = a0, U1 = a1, K0 = 0, K1 = 0;
            while (U0 | U1) {
                u64 UK0 = U0 | K0, UK1 = U1 | K1;
                bool in0 = (U0 >> lane) & 1;
                bool in1 = (U1 >> lane) & 1;
                u64 nk0 = __ballot(in0 && (ld0 & UK0) == 0ull);
                u64 nk1 = __ballot(in1 && ((lt & UK0) | (ld1 & UK1)) == 0ull);
                u64 nr0 = __ballot(in0 && (ld0 & K0) != 0ull);
                u64 nr1 = __ballot(in1 && ((lt & K0) | (ld1 & K1)) != 0ull);
                K0 |= nk0; K1 |= nk1;
                U0 &= ~(nk0 | nr0); U1 &= ~(nk1 | nr1);
            }

            if (lane == 0) {
                kept_s[par][0] = K0; kept_s[par][1] = K1;
                u64 sup0 = a0 & ~K0;               // wave 0 is sole writer of
                u64 sup1 = a1 & ~K1;               // words 2p,2p+1 this iter
                if (sup0) rem_s[w0] |= sup0;
                if (sup1) rem_s[w1] |= sup1;
            }
            // near words 2p+2..2p+5 from register bands (guard by TARGET index)
            int w2 = w0 + 2, w3 = w0 + 3, w4 = w0 + 4, w5 = w0 + 5;
            bool h2 = w2 < NW64, h3 = w3 < NW64, h4 = w4 < NW64, h5 = w5 < NW64;
            if ((K0 >> lane) & 1) {
                if (h2 && s2_0) atomicOr((unsigned long long*)&rem_s[w2], (unsigned long long)s2_0);
                if (h3 && s3_0) atomicOr((unsigned long long*)&rem_s[w3], (unsigned long long)s3_0);
                if (h4 && s4_0) atomicOr((unsigned long long*)&rem_s[w4], (unsigned long long)s4_0);
                if (h5 && s5_0) atomicOr((unsigned long long*)&rem_s[w5], (unsigned long long)s5_0);
            }
            if ((K1 >> lane) & 1) {
                if (h2 && s1_1) atomicOr((unsigned long long*)&rem_s[w2], (unsigned long long)s1_1);
                if (h3 && s2_1) atomicOr((unsigned long long*)&rem_s[w3], (unsigned long long)s2_1);
                if (h4 && s3_1) atomicOr((unsigned long long*)&rem_s[w4], (unsigned long long)s3_1);
                if (h5 && s4_1) atomicOr((unsigned long long*)&rem_s[w5], (unsigned long long)s4_1);
            }
            // swap in the prefetched bands (waitcnt lands here, fully covered)
            ld0 = nld0; ld1 = nld1; lt = nlt;
            s2_0 = ns2_0; s3_0 = ns3_0; s4_0 = ns4_0; s5_0 = ns5_0;
            s1_1 = ns1_1; s2_1 = ns2_1; s3_1 = ns3_1; s4_1 = ns4_1;
        } else {
            // ---------------- workers: pair p-1 phase ----------------
            int parw = par ^ 1;
            u64 k0 = kept_s[parw][0], k1 = kept_s[parw][1];
            int n0 = __popcll(k0);
            int nk = n0 + __popcll(k1);
            u64 below = (1ull << lane) - 1;
            if ((k0 >> lane) & 1) klist[parw][__popcll(k0 & below)] = lane;
            if ((k1 >> lane) & 1) klist[parw][n0 + __popcll(k1 & below)] = 64 + lane;

            // commit df issued at p-1 for pair p-2 (targets >= 2p+2; wave 0
            // reads 2p,2p+1 concurrently -> disjoint)
            #pragma unroll
            for (int t = 0; t < 5; ++t) {
                #pragma unroll
                for (int c = 0; c < 3; ++c) {
                    if (df[t][c])
                        atomicOr((unsigned long long*)&rem_s[2 * p + 2 + (c << 6) + lane],
                                 (unsigned long long)df[t][c]);
                }
            }

            // issue far loads for pair p-1 (targets >= 2(p-1)+6), consumed at p+1
            int q = (p > 0) ? p - 1 : 0;
            int nkc = (nk < 64) ? nk : 64;
            #pragma unroll
            for (int t = 0; t < 5; ++t) {
                int s = (wv - 1) + t * 15;
                bool has = (p > 0) && (s < nkc);
                int rr = klist[parw][has ? s : 0];
                const u64* R = M + (size_t)(q * 128 + rr) * NW64;
                #pragma unroll
                for (int c = 0; c < 3; ++c) {
                    int w = 2 * q + 6 + (c << 6) + lane;
                    df[t][c] = (has && w < NW64) ? R[w] : 0ull;
                }
            }
            // rare overflow (nk > 64): immediate load + commit (targets >=
            // 2q+6 = 2p+4 -> disjoint from wave 0's reads)
            for (int bs = 64; bs < nk; bs += 64) {
                #pragma unroll
                for (int t = 0; t < 5; ++t) {
                    int s = bs + (wv - 1) + t * 15;
                    bool has = s < nk;
                    int rr = klist[parw][has ? s : 0];
                    const u64* R = M + (size_t)(q * 128 + rr) * NW64;
                    #pragma unroll
                    for (int c = 0; c < 3; ++c) {
                        int w = 2 * q + 6 + (c << 6) + lane;
                        u64 v2 = (has && w < NW64) ? R[w] : 0ull;
                        if (v2) atomicOr((unsigned long long*)&rem_s[w], (unsigned long long)v2);
                    }
                }
            }
        }

        bar_sync();                               // kept_s/rem_s coherent
    }

    // post-loop: all remaining df target words >= 2(NPAIR-2)+6 = 170 > 166,
    // so nothing is pending. rem_s is final.

    for (int t = tid; t < NW64; t += 1024)
        rem_out[(size_t)b * NW64 + t] = rem_s[t];

    // ---- fused output tail (replaces out_kernel on the fast path) ----
    for (int t = tid; t < NTOT; t += 1024) {
        size_t idx = (size_t)b * NTOT + t;
        float4 box = sboxes[idx];
        u64 rw = rem_s[t >> 6];
        bool keep = (ssv[idx] != 0u) && !((rw >> (t & 63)) & 1ull);
        float sc = keep ? sscore[idx] : 0.0f;
        float* d = out + idx * 6;
        d[0] = box.x; d[1] = box.y; d[2] = box.z; d[3] = box.w;
        d[4] = sc;    d[5] = (float)scls[idx];
        out[(size_t)NBATCH * NTOT * 6 + idx] = keep ? 1.0f : 0.0f;
    }
}

// ---------------------------------------------------------------------------
// Fallback (small ws): original single-block NMS. Writes u32 words into the
// same u64 rem buffer (little-endian layout makes bit positions identical).
// ---------------------------------------------------------------------------
extern __shared__ unsigned char nms_smem[];

__global__ void __launch_bounds__(1024) nms_kernel(const float4* __restrict__ sboxes,
                                                   const uint32_t* __restrict__ ssv,
                                                   const int* __restrict__ nvalid_arr,
                                                   uint32_t* __restrict__ supp_out)
{
#pragma clang fp contract(off)
    int b = blockIdx.x;
    float4*   lbox = (float4*)nms_smem;
    uint32_t* supp = (uint32_t*)(nms_smem + (size_t)LDS_CAP * 16);
    uint32_t* svb  = supp + NW32;

    int nv = nvalid_arr[b];
    const float4* gb = sboxes + (size_t)b * NTOT;
    const uint32_t* gv = ssv + (size_t)b * NTOT;

    for (int t = threadIdx.x; t < NW32; t += 1024) { supp[t] = 0u; svb[t] = 0u; }
    __syncthreads();
    for (int t = threadIdx.x; t < nv; t += 1024) {
        if (t < LDS_CAP) lbox[t] = gb[t];
        if (gv[t]) atomicOr(&svb[t >> 5], 1u << (t & 31));
    }
    __syncthreads();

    for (int i = 0; i < nv; ++i) {
        uint32_t sw = supp[i >> 5];
        if ((sw >> (i & 31)) & 1u) continue;
        uint32_t vw = svb[i >> 5];
        if (!((vw >> (i & 31)) & 1u)) continue;

        float4 bi = (i < LDS_CAP) ? lbox[i] : gb[i];
        float ax1 = bi.x, ay1 = bi.y, ax2 = bi.z, ay2 = bi.w;
        float area_i = (ax2 - ax1) * (ay2 - ay1);

        for (int j = i + 1 + (int)threadIdx.x; j < nv; j += 1024) {
            float4 bj = (j < LDS_CAP) ? lbox[j] : gb[j];
            float xx1 = fmaxf(bj.x, ax1);
            float yy1 = fmaxf(bj.y, ay1);
            float xx2 = fminf(bj.z, ax2);
            float yy2 = fminf(bj.w, ay2);
            float w = fmaxf(xx2 - xx1, 0.0f);
            float h = fmaxf(yy2 - yy1, 0.0f);
            float inter  = w * h;
            float area_j = (bj.z - bj.x) * (bj.w - bj.y);
            float iou = inter / ((area_i + area_j) - inter);
            if (iou > IOU_THR_F) atomicOr(&supp[j >> 5], 1u << (j & 31));
        }
        __syncthreads();
    }

    __syncthreads();
    // u64 layout: u32 word w of image b lives at u32-index b*(2*NW64) + w
    for (int t = threadIdx.x; t < NW32; t += 1024)
        supp_out[(size_t)b * (2 * NW64) + t] = supp[t];
}

// ---------------------------------------------------------------------------
// Kernel D (fallback path only): assemble outputs
// ---------------------------------------------------------------------------
__global__ void out_kernel(const float4* __restrict__ sboxes, const float* __restrict__ sscore,
                           const int* __restrict__ scls, const uint32_t* __restrict__ ssv,
                           const u64* __restrict__ rem, float* __restrict__ out)
{
    int idx = blockIdx.x * 256 + threadIdx.x;
    if (idx >= NBATCH * NTOT) return;
    int b = idx / NTOT;
    int p = idx - b * NTOT;

    float4 box = sboxes[idx];
    u64 rw = rem[(size_t)b * NW64 + (p >> 6)];
    bool keep = (ssv[idx] != 0u) && !((rw >> (p & 63)) & 1ull);
    float sc = keep ? sscore[idx] : 0.0f;

    float* d = out + (size_t)idx * 6;
    d[0] = box.x; d[1] = box.y; d[2] = box.z; d[3] = box.w;
    d[4] = sc;    d[5] = (float)scls[idx];
    out[(size_t)NBATCH * NTOT * 6 + idx] = keep ? 1.0f : 0.0f;
}

// ---------------------------------------------------------------------------
extern "C" void kernel_launch(void* const* d_in, const int* in_sizes, int n_in,
                              void* d_out, int out_size, void* d_ws, size_t ws_size,
                              hipStream_t stream)
{
    const float* p3b = (const float*)d_in[0];
    const float* p3c = (const float*)d_in[1];
    const float* p3k = (const float*)d_in[2];
    const float* p4b = (const float*)d_in[3];
    const float* p4c = (const float*)d_in[4];
    const float* p4k = (const float*)d_in[5];
    const float* p5b = (const float*)d_in[6];
    const float* p5c = (const float*)d_in[7];
    const float* p5k = (const float*)d_in[8];
    float* out = (float*)d_out;

    // workspace carve-up (256B aligned slabs)
    char* ws = (char*)d_ws;
    size_t off = 0;
    auto alloc = [&](size_t bytes) { size_t o = off; off += (bytes + 255) & ~(size_t)255; return o; };
    const size_t BN = (size_t)NBATCH * NTOT;
    uint64_t* keys      = (uint64_t*)(ws + alloc(BN * 8));
    float4*   boxes_cat = (float4*)  (ws + alloc(BN * 16));
    float*    score     = (float*)   (ws + alloc(BN * 4));
    int*      clsidx    = (int*)     (ws + alloc(BN * 4));
    uint32_t* sv        = (uint32_t*)(ws + alloc(BN * 4));
    int*      rank_arr  = (int*)     (ws + alloc(BN * 4));
    int*      inv_arr   = (int*)     (ws + alloc(BN * 4));
    float4*   sboxes    = (float4*)  (ws + alloc(BN * 16));
    float*    sscore    = (float*)   (ws + alloc(BN * 4));
    int*      scls      = (int*)     (ws + alloc(BN * 4));
    uint32_t* ssv       = (uint32_t*)(ws + alloc(BN * 4));
    u64*      rem64     = (u64*)     (ws + alloc((size_t)NBATCH * NW64 * 8));
    int*      nvalid    = (int*)     (ws + alloc(NBATCH * 4));
    u64*      ldiag     = (u64*)     (ws + alloc((size_t)NBATCH * NW64 * 64 * 8));
    u64*      s1diag    = (u64*)     (ws + alloc((size_t)NBATCH * NW64 * 64 * 8));
    u64*      s2diag    = (u64*)     (ws + alloc((size_t)NBATCH * NW64 * 64 * 8));
    u64*      s3diag    = (u64*)     (ws + alloc((size_t)NBATCH * NW64 * 64 * 8));
    u64*      s4diag    = (u64*)     (ws + alloc((size_t)NBATCH * NW64 * 64 * 8));
    u64*      s5diag    = (u64*)     (ws + alloc((size_t)NBATCH * NW64 * 64 * 8));
    u64*      lt1       = (u64*)     (ws + alloc((size_t)NBATCH * NPAIR * 64 * 8));
    u64*      mask      = (u64*)     (ws + alloc((size_t)NBATCH * NTOT * NW64 * 8));
    bool fast = (off <= ws_size);

    int nblk = (int)((BN + 255) / 256);
    prep_kernel<<<nblk, 256, 0, stream>>>(p3b, p3c, p3k, p4b, p4c, p4k, p5b, p5c, p5k,
                                          keys, boxes_cat, score, clsidx, sv,
                                          nvalid, rank_arr);

    dim3 rpgrid(RCH, RSL, NBATCH);
    rank_partial<<<rpgrid, 256, 0, stream>>>(keys, rank_arr);

    inv_kernel<<<nblk, 256, 0, stream>>>(rank_arr, inv_arr);

    gather_kernel<<<nblk, 256, 0, stream>>>(inv_arr, boxes_cat, score, clsidx, sv,
                                            sboxes, sscore, scls, ssv,
                                            nvalid, fast ? 0 : 1);

    if (fast) {
        dim3 mgrid((NW64 + 3) / 4, (NW64 + 3) / 4, NBATCH);
        mask_build<<<mgrid, 256, 0, stream>>>(sboxes, mask, ldiag, s1diag, s2diag,
                                              s3diag, s4diag, s5diag, lt1);
        resolve_kernel<<<NBATCH, 1024, 0, stream>>>(mask, ldiag, s1diag, s2diag, s3diag,
                                                    s4diag, s5diag, lt1,
                                                    sboxes, sscore, scls, ssv,
                                                    rem64, out);
    } else {
        hipMemsetAsync(rem64, 0, (size_t)NBATCH * NW64 * 8, stream);
        size_t smem = (size_t)LDS_CAP * 16 + (size_t)NW32 * 4 * 2;
        smem = (smem + 15) & ~(size_t)15;
        hipFuncSetAttribute((const void*)nms_kernel, hipFuncAttributeMaxDynamicSharedMemorySize, (int)smem);
        nms_kernel<<<NBATCH, 1024, smem, stream>>>(sboxes, ssv, nvalid, (uint32_t*)rem64);
        out_kernel<<<nblk, 256, 0, stream>>>(sboxes, sscore, scls, ssv, rem64, out);
    }
}

// Round 19
// 431.682 us; speedup vs baseline: 1.1784x; 1.0122x over previous
//
#include <hip/hip_runtime.h>
#include <stdint.h>

#define NB3 8112
#define NB4 2028
#define NB5 507
#define NTOT 10647           // 8112 + 2028 + 507
#define NBATCH 4
#define NCLS 20
#define NW32 333             // ceil(10647 / 32)
#define NW64 167             // ceil(10647 / 64)
#define NPAIR 84             // ceil(NW64 / 2): 128-box groups for resolve
#define NTAIL 23             // NTOT - 64*(NW64-1)
#define RCH 11               // rank: element chunks of 1024 (256 thr x 4 keys)
#define RSL 6                // rank: tile slices
#define RTP 7                // rank: 256-key tiles per slice (6*7*256 >= NTOT)
#define LDS_CAP 9984         // boxes staged in LDS (fallback kernel)
#define CONF_THR_F 0.1f
#define IOU_THR_F 0.45f
// Upper midpoint of 0.45f: RN(x) > 0.45f  <=>  x > IOU_MID (0.45f mantissa LSB
// is even -> tie at the midpoint rounds DOWN). 25-bit m x 24-bit union is
// exact in f64, so (double)inter > IOU_MID*(double)union is bit-equivalent to
// the reference's f32-divide-then-compare.
#define IOU_MID ((double)IOU_THR_F + 0x1p-26)

typedef unsigned long long u64;

// ---------------------------------------------------------------------------
// Kernel A: per-box score / class argmax / sort key.
// Also zeroes nvalid/rank (folds memsets).
// ---------------------------------------------------------------------------
__global__ void prep_kernel(const float* __restrict__ p3b, const float* __restrict__ p3c, const float* __restrict__ p3k,
                            const float* __restrict__ p4b, const float* __restrict__ p4c, const float* __restrict__ p4k,
                            const float* __restrict__ p5b, const float* __restrict__ p5c, const float* __restrict__ p5k,
                            uint64_t* __restrict__ keys, float4* __restrict__ boxes_cat,
                            float* __restrict__ score, int* __restrict__ clsidx, uint32_t* __restrict__ svout,
                            int* __restrict__ nvalid, int* __restrict__ rank)
{
#pragma clang fp contract(off)
    int idx = blockIdx.x * 256 + threadIdx.x;
    if (idx < NBATCH) nvalid[idx] = 0;
    if (idx >= NBATCH * NTOT) return;
    rank[idx] = 0;
    int b = idx / NTOT;
    int i = idx - b * NTOT;

    const float* bx; const float* cf; const float* cl; int n, off;
    if (i < NB3)            { bx = p3b; cf = p3c; cl = p3k; n = NB3; off = i; }
    else if (i < NB3 + NB4) { bx = p4b; cf = p4c; cl = p4k; n = NB4; off = i - NB3; }
    else                    { bx = p5b; cf = p5c; cl = p5k; n = NB5; off = i - NB3 - NB4; }

    size_t e = (size_t)b * n + off;
    float4 box = *(const float4*)(bx + e * 4);
    float conf = cf[e];
    const float* c = cl + e * NCLS;
    float m = c[0]; int mi = 0;
    #pragma unroll
    for (int k = 1; k < NCLS; ++k) { float v = c[k]; if (v > m) { m = v; mi = k; } }

    bool valid = conf > CONF_THR_F;
    float s = valid ? conf * m : 0.0f;           // exact: single f32 mul, no fma
    uint32_t sb = __float_as_uint(s);            // s >= 0 -> bits monotonic
    keys[idx]      = ((uint64_t)sb << 32) | (uint32_t)(0xFFFFFFFFu - (uint32_t)i);
    boxes_cat[idx] = box;
    score[idx]     = s;
    clsidx[idx]    = mi;
    svout[idx]     = valid ? 1u : 0u;
}

// ---------------------------------------------------------------------------
// Kernel B1: 2D-decomposed partial rank (proven R13/R14; vectorized tile).
// ---------------------------------------------------------------------------
__global__ void __launch_bounds__(256) rank_partial(const uint64_t* __restrict__ keys,
                                                    int* __restrict__ rank)
{
    int b = blockIdx.z;
    const uint64_t* kb = keys + (size_t)b * NTOT;
    int i0 = blockIdx.x * 1024 + threadIdx.x;
    uint64_t k0 = (i0       < NTOT) ? kb[i0]       : 0ull;
    uint64_t k1 = (i0 + 256 < NTOT) ? kb[i0 + 256] : 0ull;
    uint64_t k2 = (i0 + 512 < NTOT) ? kb[i0 + 512] : 0ull;
    uint64_t k3 = (i0 + 768 < NTOT) ? kb[i0 + 768] : 0ull;
    int r0 = 0, r1 = 0, r2 = 0, r3 = 0;

    __shared__ ulonglong2 tile2[128];
    uint64_t* tile = (uint64_t*)tile2;
    for (int tt = 0; tt < RTP; ++tt) {
        int j = (blockIdx.y * RTP + tt) * 256 + threadIdx.x;
        tile[threadIdx.x] = (j < NTOT) ? kb[j] : 0ull;   // 0 never > any real key
        __syncthreads();
        #pragma unroll 4
        for (int t = 0; t < 128; ++t) {
            ulonglong2 kt = tile2[t];
            r0 += ((kt.x > k0) ? 1 : 0) + ((kt.y > k0) ? 1 : 0);
            r1 += ((kt.x > k1) ? 1 : 0) + ((kt.y > k1) ? 1 : 0);
            r2 += ((kt.x > k2) ? 1 : 0) + ((kt.y > k2) ? 1 : 0);
            r3 += ((kt.x > k3) ? 1 : 0) + ((kt.y > k3) ? 1 : 0);
        }
        __syncthreads();
    }

    int* rb = rank + (size_t)b * NTOT;
    if (i0       < NTOT) atomicAdd(&rb[i0],       r0);
    if (i0 + 256 < NTOT) atomicAdd(&rb[i0 + 256], r1);
    if (i0 + 512 < NTOT) atomicAdd(&rb[i0 + 512], r2);
    if (i0 + 768 < NTOT) atomicAdd(&rb[i0 + 768], r3);
}

// ---------------------------------------------------------------------------
// Kernel B2: invert the permutation (proven R14). 4B scattered store only.
// ---------------------------------------------------------------------------
__global__ void inv_kernel(const int* __restrict__ rank, int* __restrict__ inv)
{
    int idx = blockIdx.x * 256 + threadIdx.x;
    if (idx >= NBATCH * NTOT) return;
    int b = idx / NTOT;
    int i = idx - b * NTOT;
    inv[(size_t)b * NTOT + rank[idx]] = i;
}

// ---------------------------------------------------------------------------
// Kernel B3: gather into sorted arrays (proven R14). Random L2-resident reads
// + coalesced writes. nvalid only when fallback path needs it.
// ---------------------------------------------------------------------------
__global__ void gather_kernel(const int* __restrict__ inv,
                              const float4* __restrict__ boxes_cat,
                              const float* __restrict__ score,
                              const int* __restrict__ clsidx,
                              const uint32_t* __restrict__ sv,
                              float4* __restrict__ sboxes, float* __restrict__ sscore,
                              int* __restrict__ scls, uint32_t* __restrict__ ssv,
                              int* __restrict__ nvalid, int need_nvalid)
{
    int idx = blockIdx.x * 256 + threadIdx.x;
    if (idx >= NBATCH * NTOT) return;
    int b = idx / NTOT;
    int i = idx - b * NTOT;
    size_t base = (size_t)b * NTOT;
    int src = inv[idx];
    float4 box = boxes_cat[base + src];
    uint32_t v = sv[base + src];
    sboxes[idx] = box;
    sscore[idx] = score[base + src];
    scls[idx]   = clsidx[base + src];
    ssv[idx]    = v;
    if (need_nvalid) {
        int mv = v ? (i + 1) : 0;
        #pragma unroll
        for (int d = 32; d >= 1; d >>= 1) {
            int o = __shfl_xor(mv, d, 64);
            mv = (o > mv) ? o : mv;
        }
        if ((threadIdx.x & 63) == 0 && mv > 0) atomicMax(&nvalid[b], mv);
    }
}

// ---------------------------------------------------------------------------
// Kernel C1 (fast path): build suppression bit-matrix + band buffers
// (the R15-measured 432us version).
// IoU predicate via exact f64 midpoint comparison (see IOU_MID).
// mask[(b*NTOT + i)*NW64 + c]: bit k set iff hit && c*64+k > i && c*64+k < NTOT.
// ldiag [(b*NW64+r)*64+lane] = raw hit row & ((1<<lane)-1).
// s1..s5diag[(b*NW64+r)*64+lane] = mask word at column r+1..r+5.
// lt1[(b*NPAIR+p)*64+lane] = transpose of the (r=2p, c=2p+1) block (bit-
// symmetric hit predicate) for the joint 128-box fixpoint.
// ---------------------------------------------------------------------------
__global__ void __launch_bounds__(256) mask_build(const float4* __restrict__ sboxes,
                                                  u64* __restrict__ mask,
                                                  u64* __restrict__ ldiag,
                                                  u64* __restrict__ s1diag,
                                                  u64* __restrict__ s2diag,
                                                  u64* __restrict__ s3diag,
                                                  u64* __restrict__ s4diag,
                                                  u64* __restrict__ s5diag,
                                                  u64* __restrict__ lt1)
{
#pragma clang fp contract(off)
    int c = blockIdx.y;
    if (c < blockIdx.x * 4) return;              // whole block below diagonal
    int b = blockIdx.z;
    int sub = threadIdx.x >> 6;
    int lane = threadIdx.x & 63;
    int r = blockIdx.x * 4 + sub;

    __shared__ float4 cb[64];
    __shared__ float  ca[64];
    if (threadIdx.x < 64) {
        int j = c * 64 + threadIdx.x;
        float4 bj = sboxes[(size_t)b * NTOT + (j < NTOT ? j : NTOT - 1)];
        cb[threadIdx.x] = bj;
        ca[threadIdx.x] = (bj.z - bj.x) * (bj.w - bj.y);
    }
    __syncthreads();

    if (r >= NW64 || c < r) return;              // wave below diagonal / OOB
    int i = r * 64 + lane;
    bool live = (i < NTOT);
    float4 bi = sboxes[(size_t)b * NTOT + (live ? i : NTOT - 1)];
    float ax1 = bi.x, ay1 = bi.y, ax2 = bi.z, ay2 = bi.w;
    float area_i = (ax2 - ax1) * (ay2 - ay1);

    u64 hh = 0;
    #pragma unroll 8
    for (int k = 0; k < 64; ++k) {
        float4 bj = cb[k];
        float xx1 = fmaxf(bj.x, ax1);
        float yy1 = fmaxf(bj.y, ay1);
        float xx2 = fminf(bj.z, ax2);
        float yy2 = fminf(bj.w, ay2);
        float w = fmaxf(xx2 - xx1, 0.0f);
        float h = fmaxf(yy2 - yy1, 0.0f);
        float inter = w * h;
        float uni = (area_i + ca[k]) - inter;    // same f32 ops as reference
        bool hit = (double)inter > IOU_MID * (double)uni;   // == RN(inter/uni) > 0.45f
        hh |= (u64)hit << k;
    }

    u64 colmask = (c == NW64 - 1) ? ((1ull << NTAIL) - 1) : ~0ull;
    u64 mw = hh & colmask;

    if (live) {
        size_t bl = ((size_t)b * NW64 + r) * 64 + lane;
        if (c == r) {
            u64 gtmask = (lane < 63) ? (~0ull << (lane + 1)) : 0ull;
            mask[((size_t)b * NTOT + i) * NW64 + c] = mw & gtmask;
            ldiag[bl] = hh & ((1ull << lane) - 1);
        } else {
            mask[((size_t)b * NTOT + i) * NW64 + c] = mw;
            if (c == r + 1) s1diag[bl] = mw;
            if (c == r + 2) s2diag[bl] = mw;
            if (c == r + 3) s3diag[bl] = mw;
            if (c == r + 4) s4diag[bl] = mw;
            if (c == r + 5) s5diag[bl] = mw;
        }
    }
    // transposed band for the joint pair fixpoint (even r, c = r+1 only).
    if (c == r + 1 && (r & 1) == 0) {
        u64 ltw = 0;
        #pragma unroll 8
        for (int k = 0; k < 64; ++k) {
            u64 bw = __ballot((mw >> k) & 1ull);
            if (lane == k) ltw = bw;
        }
        lt1[((size_t)b * NPAIR + (r >> 1)) * 64 + lane] = ltw;
    }
}

// ---------------------------------------------------------------------------
// Kernel C2 (fast path): greedy resolve -- proven best (R15, 432us):
// 1024 threads, overlapped schedule; wave 0 = joint 128-box ballot fixpoint
// + near-band atomics + prefetch-first double-buffered bands (dead s1_0 load
// removed); waves 1-15 = worker df far-OR pipeline (75 slots); one barrier
// per pair; fused output tail.
// ---------------------------------------------------------------------------
static __device__ __forceinline__ void bar_sync()
{
    asm volatile("s_waitcnt lgkmcnt(0)" ::: "memory");
    __builtin_amdgcn_s_barrier();
    asm volatile("" ::: "memory");
}

static __device__ __forceinline__ u64 rfl64(u64 x)
{
    uint32_t lo = __builtin_amdgcn_readfirstlane((uint32_t)x);
    uint32_t hi = __builtin_amdgcn_readfirstlane((uint32_t)(x >> 32));
    return ((u64)hi << 32) | (u64)lo;
}

__global__ void __launch_bounds__(1024) resolve_kernel(const u64* __restrict__ mask,
                                                       const u64* __restrict__ ldiag,
                                                       const u64* __restrict__ s1diag,
                                                       const u64* __restrict__ s2diag,
                                                       const u64* __restrict__ s3diag,
                                                       const u64* __restrict__ s4diag,
                                                       const u64* __restrict__ s5diag,
                                                       const u64* __restrict__ lt1,
                                                       const float4* __restrict__ sboxes,
                                                       const float* __restrict__ sscore,
                                                       const int* __restrict__ scls,
                                                       const uint32_t* __restrict__ ssv,
                                                       u64* __restrict__ rem_out,
                                                       float* __restrict__ out)
{
    int b = blockIdx.x;
    int tid = threadIdx.x;
    int lane = tid & 63;
    int wv = tid >> 6;
    const u64* M   = mask   + (size_t)b * NTOT * NW64;
    const u64* LD  = ldiag  + (size_t)b * NW64 * 64;
    const u64* S1A = s1diag + (size_t)b * NW64 * 64;
    const u64* S2A = s2diag + (size_t)b * NW64 * 64;
    const u64* S3A = s3diag + (size_t)b * NW64 * 64;
    const u64* S4A = s4diag + (size_t)b * NW64 * 64;
    const u64* S5A = s5diag + (size_t)b * NW64 * 64;
    const u64* LT  = lt1    + (size_t)b * NPAIR * 64;

    __shared__ u64 rem_s[NW64 + 1];              // +1: word index 167 (pair tail)
    __shared__ u64 v_s[NW64 + 1];                // v_s[167] = 0 -> alive1 = 0
    __shared__ u64 kept_s[2][2];                 // parity double-buffered
    __shared__ int klist[2][128];

    for (int t = tid; t < NW64 + 1; t += 1024) rem_s[t] = 0ull;
    // v_s from ssv via per-wave ballots (wave wv covers words wv, wv+16, ...)
    for (int t = wv; t < NW64; t += 16) {
        int i = t * 64 + lane;
        uint32_t v = (i < NTOT) ? ssv[(size_t)b * NTOT + i] : 0u;
        u64 w = __ballot(v != 0u);
        if (lane == 0) v_s[t] = w;
    }
    if (tid == 0) {
        v_s[NW64] = 0ull;
        kept_s[0][0] = kept_s[0][1] = kept_s[1][0] = kept_s[1][1] = 0ull;
        klist[0][0] = 0; klist[1][0] = 0;
    }

    // wave 0's register bands for pair 0 (11 u64, double-buffered via swap)
    u64 ld0 = 0, ld1 = 0, lt = 0;
    u64 s2_0 = 0, s3_0 = 0, s4_0 = 0, s5_0 = 0;
    u64 s1_1 = 0, s2_1 = 0, s3_1 = 0, s4_1 = 0;
    if (wv == 0) {
        ld0 = LD[lane];      ld1 = LD[64 + lane];   lt = LT[lane];
        s2_0 = S2A[lane]; s3_0 = S3A[lane]; s4_0 = S4A[lane]; s5_0 = S5A[lane];
        s1_1 = S1A[64 + lane]; s2_1 = S2A[64 + lane];
        s3_1 = S3A[64 + lane]; s4_1 = S4A[64 + lane];
    }

    u64 df[5][3];                                // worker deferred far-OR payload
    #pragma unroll
    for (int t = 0; t < 5; ++t) {
        #pragma unroll
        for (int c = 0; c < 3; ++c) df[t][c] = 0ull;
    }

    bar_sync();

    for (int p = 0; p < NPAIR; ++p) {
        int par = p & 1;
        int w0 = 2 * p, w1 = 2 * p + 1;

        if (wv == 0) {
            // -------- issue next pair's band prefetch (covered by fixpoint) --
            int pn = (p + 1 < NPAIR) ? p + 1 : p;
            int i0 = 2 * pn;
            int i1 = (2 * pn + 1 < NW64) ? 2 * pn + 1 : NW64 - 1;
            u64 nld0 = LD [(size_t)i0 * 64 + lane];
            u64 nld1 = LD [(size_t)i1 * 64 + lane];
            u64 nlt  = LT [(size_t)pn * 64 + lane];
            u64 ns2_0 = S2A[(size_t)i0 * 64 + lane];
            u64 ns3_0 = S3A[(size_t)i0 * 64 + lane];
            u64 ns4_0 = S4A[(size_t)i0 * 64 + lane];
            u64 ns5_0 = S5A[(size_t)i0 * 64 + lane];
            u64 ns1_1 = S1A[(size_t)i1 * 64 + lane];
            u64 ns2_1 = S2A[(size_t)i1 * 64 + lane];
            u64 ns3_1 = S3A[(size_t)i1 * 64 + lane];
            u64 ns4_1 = S4A[(size_t)i1 * 64 + lane];

            // -------- joint 128-box fixpoint (no LDS on the chain) --------
            u64 a0 = rfl64(v_s[w0] & ~rem_s[w0]);
            u64 a1 = rfl64(v_s[w1] & ~rem_s[w1]);  // w1==167 -> pad gives 0
            u64 U0 = a0, U1 = a1, K0 = 0, K1 = 0;
            while (U0 | U1) {
                u64 UK0 = U0 | K0, UK1 = U1 | K1;
                bool in0 = (U0 >> lane) & 1;
                bool in1 = (U1 >> lane) & 1;
                u64 nk0 = __ballot(in0 && (ld0 & UK0) == 0ull);
                u64 nk1 = __ballot(in1 && ((lt & UK0) | (ld1 & UK1)) == 0ull);
                u64 nr0 = __ballot(in0 && (ld0 & K0) != 0ull);
                u64 nr1 = __ballot(in1 && ((lt & K0) | (ld1 & K1)) != 0ull);
                K0 |= nk0; K1 |= nk1;
                U0 &= ~(nk0 | nr0); U1 &= ~(nk1 | nr1);
            }

            if (lane == 0) {
                kept_s[par][0] = K0; kept_s[par][1] = K1;
                u64 sup0 = a0 & ~K0;               // wave 0 is sole writer of
                u64 sup1 = a1 & ~K1;               // words 2p,2p+1 this iter
                if (sup0) rem_s[w0] |= sup0;
                if (sup1) rem_s[w1] |= sup1;
            }
            // near words 2p+2..2p+5 from register bands (guard by TARGET index)
            int w2 = w0 + 2, w3 = w0 + 3, w4 = w0 + 4, w5 = w0 + 5;
            bool h2 = w2 < NW64, h3 = w3 < NW64, h4 = w4 < NW64, h5 = w5 < NW64;
            if ((K0 >> lane) & 1) {
                if (h2 && s2_0) atomicOr((unsigned long long*)&rem_s[w2], (unsigned long long)s2_0);
                if (h3 && s3_0) atomicOr((unsigned long long*)&rem_s[w3], (unsigned long long)s3_0);
                if (h4 && s4_0) atomicOr((unsigned long long*)&rem_s[w4], (unsigned long long)s4_0);
                if (h5 && s5_0) atomicOr((unsigned long long*)&rem_s[w5], (unsigned long long)s5_0);
            }
            if ((K1 >> lane) & 1) {
                if (h2 && s1_1) atomicOr((unsigned long long*)&rem_s[w2], (unsigned long long)s1_1);
                if (h3 && s2_1) atomicOr((unsigned long long*)&rem_s[w3], (unsigned long long)s2_1);
                if (h4 && s3_1) atomicOr((unsigned long long*)&rem_s[w4], (unsigned long long)s3_1);
                if (h5 && s4_1) atomicOr((unsigned long long*)&rem_s[w5], (unsigned long long)s4_1);
            }
            // swap in the prefetched bands (waitcnt lands here, fully covered)
            ld0 = nld0; ld1 = nld1; lt = nlt;
            s2_0 = ns2_0; s3_0 = ns3_0; s4_0 = ns4_0; s5_0 = ns5_0;
            s1_1 = ns1_1; s2_1 = ns2_1; s3_1 = ns3_1; s4_1 = ns4_1;
        } else {
            // ---------------- workers: pair p-1 phase ----------------
            int parw = par ^ 1;
            u64 k0 = kept_s[parw][0], k1 = kept_s[parw][1];
            int n0 = __popcll(k0);
            int nk = n0 + __popcll(k1);
            u64 below = (1ull << lane) - 1;
            if ((k0 >> lane) & 1) klist[parw][__popcll(k0 & below)] = lane;
            if ((k1 >> lane) & 1) klist[parw][n0 + __popcll(k1 & below)] = 64 + lane;

            // commit df issued at p-1 for pair p-2 (targets >= 2p+2; wave 0
            // reads 2p,2p+1 concurrently -> disjoint)
            #pragma unroll
            for (int t = 0; t < 5; ++t) {
                #pragma unroll
                for (int c = 0; c < 3; ++c) {
                    if (df[t][c])
                        atomicOr((unsigned long long*)&rem_s[2 * p + 2 + (c << 6) + lane],
                                 (unsigned long long)df[t][c]);
                }
            }

            // issue far loads for pair p-1 (targets >= 2(p-1)+6), consumed at p+1
            int q = (p > 0) ? p - 1 : 0;
            int nkc = (nk < 64) ? nk : 64;
            #pragma unroll
            for (int t = 0; t < 5; ++t) {
                int s = (wv - 1) + t * 15;
                bool has = (p > 0) && (s < nkc);
                int rr = klist[parw][has ? s : 0];
                const u64* R = M + (size_t)(q * 128 + rr) * NW64;
                #pragma unroll
                for (int c = 0; c < 3; ++c) {
                    int w = 2 * q + 6 + (c << 6) + lane;
                    df[t][c] = (has && w < NW64) ? R[w] : 0ull;
                }
            }
            // rare overflow (nk > 64): immediate load + commit (targets >=
            // 2q+6 = 2p+4 -> disjoint from wave 0's reads)
            for (int bs = 64; bs < nk; bs += 64) {
                #pragma unroll
                for (int t = 0; t < 5; ++t) {
                    int s = bs + (wv - 1) + t * 15;
                    bool has = s < nk;
                    int rr = klist[parw][has ? s : 0];
                    const u64* R = M + (size_t)(q * 128 + rr) * NW64;
                    #pragma unroll
                    for (int c = 0; c < 3; ++c) {
                        int w = 2 * q + 6 + (c << 6) + lane;
                        u64 v2 = (has && w < NW64) ? R[w] : 0ull;
                        if (v2) atomicOr((unsigned long long*)&rem_s[w], (unsigned long long)v2);
                    }
                }
            }
        }

        bar_sync();                               // kept_s/rem_s coherent
    }

    // post-loop: all remaining df target words >= 2(NPAIR-2)+6 = 170 > 166,
    // so nothing is pending. rem_s is final.

    for (int t = tid; t < NW64; t += 1024)
        rem_out[(size_t)b * NW64 + t] = rem_s[t];

    // ---- fused output tail (replaces out_kernel on the fast path) ----
    for (int t = tid; t < NTOT; t += 1024) {
        size_t idx = (size_t)b * NTOT + t;
        float4 box = sboxes[idx];
        u64 rw = rem_s[t >> 6];
        bool keep = (ssv[idx] != 0u) && !((rw >> (t & 63)) & 1ull);
        float sc = keep ? sscore[idx] : 0.0f;
        float* d = out + idx * 6;
        d[0] = box.x; d[1] = box.y; d[2] = box.z; d[3] = box.w;
        d[4] = sc;    d[5] = (float)scls[idx];
        out[(size_t)NBATCH * NTOT * 6 + idx] = keep ? 1.0f : 0.0f;
    }
}

// ---------------------------------------------------------------------------
// Fallback (small ws): original single-block NMS. Writes u32 words into the
// same u64 rem buffer (little-endian layout makes bit positions identical).
// ---------------------------------------------------------------------------
extern __shared__ unsigned char nms_smem[];

__global__ void __launch_bounds__(1024) nms_kernel(const float4* __restrict__ sboxes,
                                                   const uint32_t* __restrict__ ssv,
                                                   const int* __restrict__ nvalid_arr,
                                                   uint32_t* __restrict__ supp_out)
{
#pragma clang fp contract(off)
    int b = blockIdx.x;
    float4*   lbox = (float4*)nms_smem;
    uint32_t* supp = (uint32_t*)(nms_smem + (size_t)LDS_CAP * 16);
    uint32_t* svb  = supp + NW32;

    int nv = nvalid_arr[b];
    const float4* gb = sboxes + (size_t)b * NTOT;
    const uint32_t* gv = ssv + (size_t)b * NTOT;

    for (int t = threadIdx.x; t < NW32; t += 1024) { supp[t] = 0u; svb[t] = 0u; }
    __syncthreads();
    for (int t = threadIdx.x; t < nv; t += 1024) {
        if (t < LDS_CAP) lbox[t] = gb[t];
        if (gv[t]) atomicOr(&svb[t >> 5], 1u << (t & 31));
    }
    __syncthreads();

    for (int i = 0; i < nv; ++i) {
        uint32_t sw = supp[i >> 5];
        if ((sw >> (i & 31)) & 1u) continue;
        uint32_t vw = svb[i >> 5];
        if (!((vw >> (i & 31)) & 1u)) continue;

        float4 bi = (i < LDS_CAP) ? lbox[i] : gb[i];
        float ax1 = bi.x, ay1 = bi.y, ax2 = bi.z, ay2 = bi.w;
        float area_i = (ax2 - ax1) * (ay2 - ay1);

        for (int j = i + 1 + (int)threadIdx.x; j < nv; j += 1024) {
            float4 bj = (j < LDS_CAP) ? lbox[j] : gb[j];
            float xx1 = fmaxf(bj.x, ax1);
            float yy1 = fmaxf(bj.y, ay1);
            float xx2 = fminf(bj.z, ax2);
            float yy2 = fminf(bj.w, ay2);
            float w = fmaxf(xx2 - xx1, 0.0f);
            float h = fmaxf(yy2 - yy1, 0.0f);
            float inter  = w * h;
            float area_j = (bj.z - bj.x) * (bj.w - bj.y);
            float iou = inter / ((area_i + area_j) - inter);
            if (iou > IOU_THR_F) atomicOr(&supp[j >> 5], 1u << (j & 31));
        }
        __syncthreads();
    }

    __syncthreads();
    // u64 layout: u32 word w of image b lives at u32-index b*(2*NW64) + w
    for (int t = threadIdx.x; t < NW32; t += 1024)
        supp_out[(size_t)b * (2 * NW64) + t] = supp[t];
}

// ---------------------------------------------------------------------------
// Kernel D (fallback path only): assemble outputs
// ---------------------------------------------------------------------------
__global__ void out_kernel(const float4* __restrict__ sboxes, const float* __restrict__ sscore,
                           const int* __restrict__ scls, const uint32_t* __restrict__ ssv,
                           const u64* __restrict__ rem, float* __restrict__ out)
{
    int idx = blockIdx.x * 256 + threadIdx.x;
    if (idx >= NBATCH * NTOT) return;
    int b = idx / NTOT;
    int p = idx - b * NTOT;

    float4 box = sboxes[idx];
    u64 rw = rem[(size_t)b * NW64 + (p >> 6)];
    bool keep = (ssv[idx] != 0u) && !((rw >> (p & 63)) & 1ull);
    float sc = keep ? sscore[idx] : 0.0f;

    float* d = out + (size_t)idx * 6;
    d[0] = box.x; d[1] = box.y; d[2] = box.z; d[3] = box.w;
    d[4] = sc;    d[5] = (float)scls[idx];
    out[(size_t)NBATCH * NTOT * 6 + idx] = keep ? 1.0f : 0.0f;
}

// ---------------------------------------------------------------------------
extern "C" void kernel_launch(void* const* d_in, const int* in_sizes, int n_in,
                              void* d_out, int out_size, void* d_ws, size_t ws_size,
                              hipStream_t stream)
{
    const float* p3b = (const float*)d_in[0];
    const float* p3c = (const float*)d_in[1];
    const float* p3k = (const float*)d_in[2];
    const float* p4b = (const float*)d_in[3];
    const float* p4c = (const float*)d_in[4];
    const float* p4k = (const float*)d_in[5];
    const float* p5b = (const float*)d_in[6];
    const float* p5c = (const float*)d_in[7];
    const float* p5k = (const float*)d_in[8];
    float* out = (float*)d_out;

    // workspace carve-up (256B aligned slabs)
    char* ws = (char*)d_ws;
    size_t off = 0;
    auto alloc = [&](size_t bytes) { size_t o = off; off += (bytes + 255) & ~(size_t)255; return o; };
    const size_t BN = (size_t)NBATCH * NTOT;
    uint64_t* keys      = (uint64_t*)(ws + alloc(BN * 8));
    float4*   boxes_cat = (float4*)  (ws + alloc(BN * 16));
    float*    score     = (float*)   (ws + alloc(BN * 4));
    int*      clsidx    = (int*)     (ws + alloc(BN * 4));
    uint32_t* sv        = (uint32_t*)(ws + alloc(BN * 4));
    int*      rank_arr  = (int*)     (ws + alloc(BN * 4));
    int*      inv_arr   = (int*)     (ws + alloc(BN * 4));
    float4*   sboxes    = (float4*)  (ws + alloc(BN * 16));
    float*    sscore    = (float*)   (ws + alloc(BN * 4));
    int*      scls      = (int*)     (ws + alloc(BN * 4));
    uint32_t* ssv       = (uint32_t*)(ws + alloc(BN * 4));
    u64*      rem64     = (u64*)     (ws + alloc((size_t)NBATCH * NW64 * 8));
    int*      nvalid    = (int*)     (ws + alloc(NBATCH * 4));
    u64*      ldiag     = (u64*)     (ws + alloc((size_t)NBATCH * NW64 * 64 * 8));
    u64*      s1diag    = (u64*)     (ws + alloc((size_t)NBATCH * NW64 * 64 * 8));
    u64*      s2diag    = (u64*)     (ws + alloc((size_t)NBATCH * NW64 * 64 * 8));
    u64*      s3diag    = (u64*)     (ws + alloc((size_t)NBATCH * NW64 * 64 * 8));
    u64*      s4diag    = (u64*)     (ws + alloc((size_t)NBATCH * NW64 * 64 * 8));
    u64*      s5diag    = (u64*)     (ws + alloc((size_t)NBATCH * NW64 * 64 * 8));
    u64*      lt1       = (u64*)     (ws + alloc((size_t)NBATCH * NPAIR * 64 * 8));
    u64*      mask      = (u64*)     (ws + alloc((size_t)NBATCH * NTOT * NW64 * 8));
    bool fast = (off <= ws_size);

    int nblk = (int)((BN + 255) / 256);
    prep_kernel<<<nblk, 256, 0, stream>>>(p3b, p3c, p3k, p4b, p4c, p4k, p5b, p5c, p5k,
                                          keys, boxes_cat, score, clsidx, sv,
                                          nvalid, rank_arr);

    dim3 rpgrid(RCH, RSL, NBATCH);
    rank_partial<<<rpgrid, 256, 0, stream>>>(keys, rank_arr);

    inv_kernel<<<nblk, 256, 0, stream>>>(rank_arr, inv_arr);

    gather_kernel<<<nblk, 256, 0, stream>>>(inv_arr, boxes_cat, score, clsidx, sv,
                                            sboxes, sscore, scls, ssv,
                                            nvalid, fast ? 0 : 1);

    if (fast) {
        dim3 mgrid((NW64 + 3) / 4, NW64, NBATCH);
        mask_build<<<mgrid, 256, 0, stream>>>(sboxes, mask, ldiag, s1diag, s2diag,
                                              s3diag, s4diag, s5diag, lt1);
        resolve_kernel<<<NBATCH, 1024, 0, stream>>>(mask, ldiag, s1diag, s2diag, s3diag,
                                                    s4diag, s5diag, lt1,
                                                    sboxes, sscore, scls, ssv,
                                                    rem64, out);
    } else {
        hipMemsetAsync(rem64, 0, (size_t)NBATCH * NW64 * 8, stream);
        size_t smem = (size_t)LDS_CAP * 16 + (size_t)NW32 * 4 * 2;
        smem = (smem + 15) & ~(size_t)15;
        hipFuncSetAttribute((const void*)nms_kernel, hipFuncAttributeMaxDynamicSharedMemorySize, (int)smem);
        nms_kernel<<<NBATCH, 1024, smem, stream>>>(sboxes, ssv, nvalid, (uint32_t*)rem64);
        out_kernel<<<nblk, 256, 0, stream>>>(sboxes, sscore, scls, ssv, rem64, out);
    }
}